// Round 1
// baseline (3999.313 us; speedup 1.0000x reference)
//
#include <hip/hip_runtime.h>
#include <hip/hip_bf16.h>

typedef __hip_bfloat16 bf16;

#define N_NODES 50000
#define N_EDGES 400000
#define HID 128
#define MSG 128

// ---------------------------------------------------------------------------
// Tiled f32 GEMM:  O[M,J] = concat(A1[M,K1], A2[M,K2]) @ W[J,K]^T + bias[J]
// Output written as bf16. TM=TN=64, TK=16, 256 threads, 4x4 micro-tile.
// ---------------------------------------------------------------------------
#define TM 64
#define TN 64
#define TK 16

__global__ __launch_bounds__(256)
void gemm_bias_kernel(const float* __restrict__ A1, int K1,
                      const float* __restrict__ A2, int K2,
                      const float* __restrict__ W,     // [J, K] row-major
                      const float* __restrict__ bias,  // [J] or nullptr
                      bf16* __restrict__ O, int M, int J) {
    const int K = K1 + K2;
    __shared__ float As[TK][TM + 1];
    __shared__ float Ws[TK][TN + 1];

    const int bm = blockIdx.x * TM;
    const int bn = blockIdx.y * TN;
    const int tid = threadIdx.x;
    const int tx = tid & 15;       // 0..15 -> 4 output cols
    const int ty = tid >> 4;       // 0..15 -> 4 output rows

    float acc[4][4] = {};

    for (int k0 = 0; k0 < K; k0 += TK) {
        // stage A tile (64 rows x 16 k)
        #pragma unroll
        for (int i = tid; i < TM * TK; i += 256) {
            int m  = i / TK;
            int kk = i % TK;
            int gm = bm + m;
            int gk = k0 + kk;
            float v = 0.0f;
            if (gm < M) {
                v = (gk < K1) ? A1[(size_t)gm * K1 + gk]
                              : A2[(size_t)gm * K2 + (gk - K1)];
            }
            As[kk][m] = v;
        }
        // stage W tile (64 cols x 16 k)
        #pragma unroll
        for (int i = tid; i < TN * TK; i += 256) {
            int n  = i / TK;
            int kk = i % TK;
            int gn = bn + n;
            int gk = k0 + kk;
            Ws[kk][n] = (gn < J) ? W[(size_t)gn * K + gk] : 0.0f;
        }
        __syncthreads();

        #pragma unroll
        for (int kk = 0; kk < TK; ++kk) {
            float a[4], b[4];
            #pragma unroll
            for (int i = 0; i < 4; ++i) a[i] = As[kk][ty * 4 + i];
            #pragma unroll
            for (int j = 0; j < 4; ++j) b[j] = Ws[kk][tx * 4 + j];
            #pragma unroll
            for (int i = 0; i < 4; ++i)
                #pragma unroll
                for (int j = 0; j < 4; ++j)
                    acc[i][j] += a[i] * b[j];
        }
        __syncthreads();
    }

    #pragma unroll
    for (int i = 0; i < 4; ++i) {
        int gm = bm + ty * 4 + i;
        if (gm >= M) continue;
        #pragma unroll
        for (int j = 0; j < 4; ++j) {
            int gn = bn + tx * 4 + j;
            float v = acc[i][j] + (bias ? bias[gn] : 0.0f);
            O[(size_t)gm * J + gn] = __float2bfloat16(v);
        }
    }
}

// ---------------------------------------------------------------------------
// Build Wsd[256][256]: rows 0..127 -> S weights (W_msg cols 0..255),
// rows 128..255 -> D weights (W_msg cols 256..511).
// ---------------------------------------------------------------------------
__global__ __launch_bounds__(256)
void prep_wsd_kernel(const float* __restrict__ W_msg, float* __restrict__ Wsd) {
    int gid = blockIdx.x * 256 + threadIdx.x;   // 256*256 total
    int jj = gid >> 8;
    int k  = gid & 255;
    float v = (jj < 128) ? W_msg[jj * 512 + k]
                         : W_msg[(jj - 128) * 512 + 256 + k];
    Wsd[jj * 256 + k] = v;
}

// ---------------------------------------------------------------------------
// Degree histogram over dst (fixed across rounds)
// ---------------------------------------------------------------------------
__global__ __launch_bounds__(256)
void deg_kernel(const int* __restrict__ dst, int* __restrict__ cnt, int E) {
    int e = blockIdx.x * 256 + threadIdx.x;
    if (e < E) atomicAdd(&cnt[dst[e]], 1);
}

// ---------------------------------------------------------------------------
// Scatter: segS[dst[e]] += S[src[e]]  (S = SD[:, 0:128], bf16)
// 16 threads per edge, 8 features each (one 16B vector load).
// ---------------------------------------------------------------------------
__global__ __launch_bounds__(256)
void scatter_kernel(const bf16* __restrict__ SD,
                    const int* __restrict__ src, const int* __restrict__ dst,
                    float* __restrict__ segS, int E) {
    int gid = blockIdx.x * 256 + threadIdx.x;
    int e    = gid >> 4;
    int part = gid & 15;
    if (e >= E) return;
    int s = src[e];
    int d = dst[e];
    const float4 raw = *reinterpret_cast<const float4*>(SD + (size_t)s * 256 + part * 8);
    const bf16* b = reinterpret_cast<const bf16*>(&raw);
    float* out = segS + (size_t)d * 128 + part * 8;
    #pragma unroll
    for (int j = 0; j < 8; ++j)
        atomicAdd(out + j, __bfloat162float(b[j]));
}

// ---------------------------------------------------------------------------
// c[v][j] = cnt>0 ? segS[v][j]/cnt + D[v][j] + b_msg[j] : 0   (in-place segS)
// ---------------------------------------------------------------------------
__global__ __launch_bounds__(256)
void mean_c_kernel(float* __restrict__ segS, const bf16* __restrict__ SD,
                   const int* __restrict__ cnt, const float* __restrict__ b_msg,
                   int N) {
    int gid = blockIdx.x * 256 + threadIdx.x;
    int v = gid >> 7;
    int j = gid & 127;
    if (v >= N) return;
    int c = cnt[v];
    float val = 0.0f;
    if (c > 0) {
        float Dv = __bfloat162float(SD[(size_t)v * 256 + 128 + j]);
        val = segS[gid] / (float)c + Dv + b_msg[j];
    }
    segS[gid] = val;
}

// ---------------------------------------------------------------------------
// GRU gates: h = (1-z)*n + z*h
// ---------------------------------------------------------------------------
__global__ __launch_bounds__(256)
void gru_kernel(const bf16* __restrict__ GI, const bf16* __restrict__ GH,
                float* __restrict__ h, int N) {
    int gid = blockIdx.x * 256 + threadIdx.x;
    int v = gid >> 7;
    int j = gid & 127;
    if (v >= N) return;
    size_t base = (size_t)v * 384;
    float ir = __bfloat162float(GI[base + j]);
    float iz = __bfloat162float(GI[base + 128 + j]);
    float in_ = __bfloat162float(GI[base + 256 + j]);
    float hr = __bfloat162float(GH[base + j]);
    float hz = __bfloat162float(GH[base + 128 + j]);
    float hn = __bfloat162float(GH[base + 256 + j]);
    float r = 1.0f / (1.0f + expf(-(ir + hr)));
    float z = 1.0f / (1.0f + expf(-(iz + hz)));
    float n = tanhf(in_ + r * hn);
    size_t hi = (size_t)v * 128 + j;
    h[hi] = (1.0f - z) * n + z * h[hi];
}

// ---------------------------------------------------------------------------
extern "C" void kernel_launch(void* const* d_in, const int* in_sizes, int n_in,
                              void* d_out, int out_size, void* d_ws, size_t ws_size,
                              hipStream_t stream) {
    const float* x     = (const float*)d_in[0];
    const float* h0    = (const float*)d_in[1];
    const float* W_msg = (const float*)d_in[2];
    const float* b_msg = (const float*)d_in[3];
    const float* w_ih  = (const float*)d_in[4];
    const float* w_hh  = (const float*)d_in[5];
    const float* b_ih  = (const float*)d_in[6];
    const float* b_hh  = (const float*)d_in[7];
    const int*   src   = (const int*)d_in[8];
    const int*   dst   = (const int*)d_in[9];
    float* h = (float*)d_out;

    char* ws = (char*)d_ws;
    size_t off = 0;
    auto alloc = [&](size_t bytes) -> void* {
        void* p = ws + off;
        off = (off + bytes + 255) & ~(size_t)255;
        return p;
    };
    int*   cnt  = (int*)  alloc((size_t)N_NODES * 4);
    float* Wsd  = (float*)alloc(256 * 256 * 4);
    bf16*  SD   = (bf16*) alloc((size_t)N_NODES * 256 * 2);
    float* segS = (float*)alloc((size_t)N_NODES * 128 * 4);
    bf16*  GI   = (bf16*) alloc((size_t)N_NODES * 384 * 2);
    bf16*  GH   = (bf16*) alloc((size_t)N_NODES * 384 * 2);

    hipMemsetAsync(cnt, 0, (size_t)N_NODES * 4, stream);
    deg_kernel<<<(N_EDGES + 255) / 256, 256, 0, stream>>>(dst, cnt, N_EDGES);
    prep_wsd_kernel<<<(256 * 256) / 256, 256, 0, stream>>>(W_msg, Wsd);
    hipMemcpyAsync(h, h0, (size_t)N_NODES * HID * 4, hipMemcpyDeviceToDevice, stream);

    dim3 blk(256);
    dim3 g_sd((N_NODES + TM - 1) / TM, 256 / TN);
    dim3 g_g((N_NODES + TM - 1) / TM, 384 / TN);

    for (int r = 0; r < 2; ++r) {
        // SD = [x|h] @ Wsd^T  (no bias; b_msg folded into mean_c)
        gemm_bias_kernel<<<g_sd, blk, 0, stream>>>(x, 128, h, 128, Wsd, nullptr,
                                                   SD, N_NODES, 256);
        hipMemsetAsync(segS, 0, (size_t)N_NODES * 128 * 4, stream);
        scatter_kernel<<<((size_t)N_EDGES * 16 + 255) / 256, 256, 0, stream>>>(
            SD, src, dst, segS, N_EDGES);
        mean_c_kernel<<<(N_NODES * 128 + 255) / 256, 256, 0, stream>>>(
            segS, SD, cnt, b_msg, N_NODES);
        // GI = [x|c] @ w_ih^T + b_ih
        gemm_bias_kernel<<<g_g, blk, 0, stream>>>(x, 128, segS, 128, w_ih, b_ih,
                                                  GI, N_NODES, 384);
        // GH = h @ w_hh^T + b_hh
        gemm_bias_kernel<<<g_g, blk, 0, stream>>>(h, 128, (const float*)nullptr, 0,
                                                  w_hh, b_hh, GH, N_NODES, 384);
        gru_kernel<<<(N_NODES * 128 + 255) / 256, 256, 0, stream>>>(GI, GH, h, N_NODES);
    }
}

// Round 2
// 1287.029 us; speedup vs baseline: 3.1074x; 3.1074x over previous
//
#include <hip/hip_runtime.h>
#include <hip/hip_bf16.h>

typedef __hip_bfloat16 bf16;

#define N_NODES 50000
#define N_EDGES 400000
#define HID 128
#define MSG 128

// ---------------------------------------------------------------------------
// Tiled f32 GEMM:  O[M,J] = concat(A1[M,K1], A2[M,K2]) @ W[J,K]^T + bias[J]
// Output written as bf16. TM=TN=64, TK=16, 256 threads, 4x4 micro-tile.
// ---------------------------------------------------------------------------
#define TM 64
#define TN 64
#define TK 16

__global__ __launch_bounds__(256)
void gemm_bias_kernel(const float* __restrict__ A1, int K1,
                      const float* __restrict__ A2, int K2,
                      const float* __restrict__ W,     // [J, K] row-major
                      const float* __restrict__ bias,  // [J] or nullptr
                      bf16* __restrict__ O, int M, int J) {
    const int K = K1 + K2;
    __shared__ float As[TK][TM + 1];
    __shared__ float Ws[TK][TN + 1];

    const int bm = blockIdx.x * TM;
    const int bn = blockIdx.y * TN;
    const int tid = threadIdx.x;
    const int tx = tid & 15;       // 0..15 -> 4 output cols
    const int ty = tid >> 4;       // 0..15 -> 4 output rows

    float acc[4][4] = {};

    for (int k0 = 0; k0 < K; k0 += TK) {
        // stage A tile (64 rows x 16 k)
        #pragma unroll
        for (int i = tid; i < TM * TK; i += 256) {
            int m  = i / TK;
            int kk = i % TK;
            int gm = bm + m;
            int gk = k0 + kk;
            float v = 0.0f;
            if (gm < M) {
                v = (gk < K1) ? A1[(size_t)gm * K1 + gk]
                              : A2[(size_t)gm * K2 + (gk - K1)];
            }
            As[kk][m] = v;
        }
        // stage W tile (64 cols x 16 k)
        #pragma unroll
        for (int i = tid; i < TN * TK; i += 256) {
            int n  = i / TK;
            int kk = i % TK;
            int gn = bn + n;
            int gk = k0 + kk;
            Ws[kk][n] = (gn < J) ? W[(size_t)gn * K + gk] : 0.0f;
        }
        __syncthreads();

        #pragma unroll
        for (int kk = 0; kk < TK; ++kk) {
            float a[4], b[4];
            #pragma unroll
            for (int i = 0; i < 4; ++i) a[i] = As[kk][ty * 4 + i];
            #pragma unroll
            for (int j = 0; j < 4; ++j) b[j] = Ws[kk][tx * 4 + j];
            #pragma unroll
            for (int i = 0; i < 4; ++i)
                #pragma unroll
                for (int j = 0; j < 4; ++j)
                    acc[i][j] += a[i] * b[j];
        }
        __syncthreads();
    }

    #pragma unroll
    for (int i = 0; i < 4; ++i) {
        int gm = bm + ty * 4 + i;
        if (gm >= M) continue;
        #pragma unroll
        for (int j = 0; j < 4; ++j) {
            int gn = bn + tx * 4 + j;
            float v = acc[i][j] + (bias ? bias[gn] : 0.0f);
            O[(size_t)gm * J + gn] = __float2bfloat16(v);
        }
    }
}

// ---------------------------------------------------------------------------
// Build Wsd[256][256]: rows 0..127 -> S weights (W_msg cols 0..255),
// rows 128..255 -> D weights (W_msg cols 256..511).
// ---------------------------------------------------------------------------
__global__ __launch_bounds__(256)
void prep_wsd_kernel(const float* __restrict__ W_msg, float* __restrict__ Wsd) {
    int gid = blockIdx.x * 256 + threadIdx.x;   // 256*256 total
    int jj = gid >> 8;
    int k  = gid & 255;
    float v = (jj < 128) ? W_msg[jj * 512 + k]
                         : W_msg[(jj - 128) * 512 + 256 + k];
    Wsd[jj * 256 + k] = v;
}

// ---------------------------------------------------------------------------
// Degree histogram over dst (graph fixed across rounds)
// ---------------------------------------------------------------------------
__global__ __launch_bounds__(256)
void deg_kernel(const int* __restrict__ dst, int* __restrict__ cnt, int E) {
    int e = blockIdx.x * 256 + threadIdx.x;
    if (e < E) atomicAdd(&cnt[dst[e]], 1);
}

// ---------------------------------------------------------------------------
// Exclusive prefix scan of cnt -> off (single block, 1024 threads).
// N=50000: each thread owns a ~49-node chunk; Hillis-Steele over 1024 partials.
// ---------------------------------------------------------------------------
__global__ __launch_bounds__(1024)
void scan_kernel(const int* __restrict__ cnt, int* __restrict__ off, int N) {
    __shared__ int psum[1024];
    const int t = threadIdx.x;
    const int chunk = (N + 1023) / 1024;
    const int lo = t * chunk;
    const int hi = min(lo + chunk, N);
    int s = 0;
    for (int i = lo; i < hi; ++i) s += cnt[i];
    psum[t] = s;
    __syncthreads();
    for (int d = 1; d < 1024; d <<= 1) {
        int v = (t >= d) ? psum[t - d] : 0;
        __syncthreads();
        psum[t] += v;
        __syncthreads();
    }
    int run = (t > 0) ? psum[t - 1] : 0;   // exclusive base of this chunk
    for (int i = lo; i < hi; ++i) {
        off[i] = run;
        run += cnt[i];
    }
    if (t == 1023) off[N] = run;
}

// ---------------------------------------------------------------------------
// Fill CSR: csr[off[dst[e]] + pos++] = src[e]
// ---------------------------------------------------------------------------
__global__ __launch_bounds__(256)
void fill_csr_kernel(const int* __restrict__ src, const int* __restrict__ dst,
                     const int* __restrict__ off, int* __restrict__ cursor,
                     int* __restrict__ csr, int E) {
    int e = blockIdx.x * 256 + threadIdx.x;
    if (e >= E) return;
    int d = dst[e];
    int pos = atomicAdd(&cursor[d], 1);
    csr[off[d] + pos] = src[e];
}

// ---------------------------------------------------------------------------
// Gather-aggregate + fused mean/D/bias epilogue.
// One wave per node; lane i owns features {2i, 2i+1}.
// c[v] = deg>0 ? (sum_e S[src_e]) / deg + D[v] + b_msg : 0
// S = SD[:, 0:128], D = SD[:, 128:256] (bf16).
// ---------------------------------------------------------------------------
__global__ __launch_bounds__(256)
void agg_kernel(const bf16* __restrict__ SD, const int* __restrict__ csr,
                const int* __restrict__ off, const int* __restrict__ cnt,
                const float* __restrict__ b_msg, float* __restrict__ c, int N) {
    const int v    = (blockIdx.x * 256 + threadIdx.x) >> 6;
    const int lane = threadIdx.x & 63;
    if (v >= N) return;
    const int deg  = cnt[v];
    const int base = off[v];

    float accx0 = 0.f, accy0 = 0.f, accx1 = 0.f, accy1 = 0.f;
    int k = 0;
    for (; k + 1 < deg; k += 2) {
        int s0 = csr[base + k];
        int s1 = csr[base + k + 1];
        unsigned u0 = *reinterpret_cast<const unsigned*>(SD + (size_t)s0 * 256 + lane * 2);
        unsigned u1 = *reinterpret_cast<const unsigned*>(SD + (size_t)s1 * 256 + lane * 2);
        accx0 += __uint_as_float(u0 << 16);
        accy0 += __uint_as_float(u0 & 0xffff0000u);
        accx1 += __uint_as_float(u1 << 16);
        accy1 += __uint_as_float(u1 & 0xffff0000u);
    }
    if (k < deg) {
        int s0 = csr[base + k];
        unsigned u0 = *reinterpret_cast<const unsigned*>(SD + (size_t)s0 * 256 + lane * 2);
        accx0 += __uint_as_float(u0 << 16);
        accy0 += __uint_as_float(u0 & 0xffff0000u);
    }

    float2 outv = {0.f, 0.f};
    if (deg > 0) {
        unsigned ud = *reinterpret_cast<const unsigned*>(SD + (size_t)v * 256 + 128 + lane * 2);
        float inv = 1.0f / (float)deg;
        const float2 bm = *reinterpret_cast<const float2*>(b_msg + lane * 2);
        outv.x = (accx0 + accx1) * inv + __uint_as_float(ud << 16)         + bm.x;
        outv.y = (accy0 + accy1) * inv + __uint_as_float(ud & 0xffff0000u) + bm.y;
    }
    *reinterpret_cast<float2*>(c + (size_t)v * 128 + lane * 2) = outv;
}

// ---------------------------------------------------------------------------
// GRU gates: h = (1-z)*n + z*h
// ---------------------------------------------------------------------------
__global__ __launch_bounds__(256)
void gru_kernel(const bf16* __restrict__ GI, const bf16* __restrict__ GH,
                float* __restrict__ h, int N) {
    int gid = blockIdx.x * 256 + threadIdx.x;
    int v = gid >> 7;
    int j = gid & 127;
    if (v >= N) return;
    size_t base = (size_t)v * 384;
    float ir = __bfloat162float(GI[base + j]);
    float iz = __bfloat162float(GI[base + 128 + j]);
    float in_ = __bfloat162float(GI[base + 256 + j]);
    float hr = __bfloat162float(GH[base + j]);
    float hz = __bfloat162float(GH[base + 128 + j]);
    float hn = __bfloat162float(GH[base + 256 + j]);
    float r = 1.0f / (1.0f + expf(-(ir + hr)));
    float z = 1.0f / (1.0f + expf(-(iz + hz)));
    float n = tanhf(in_ + r * hn);
    size_t hi = (size_t)v * 128 + j;
    h[hi] = (1.0f - z) * n + z * h[hi];
}

// ---------------------------------------------------------------------------
extern "C" void kernel_launch(void* const* d_in, const int* in_sizes, int n_in,
                              void* d_out, int out_size, void* d_ws, size_t ws_size,
                              hipStream_t stream) {
    const float* x     = (const float*)d_in[0];
    const float* h0    = (const float*)d_in[1];
    const float* W_msg = (const float*)d_in[2];
    const float* b_msg = (const float*)d_in[3];
    const float* w_ih  = (const float*)d_in[4];
    const float* w_hh  = (const float*)d_in[5];
    const float* b_ih  = (const float*)d_in[6];
    const float* b_hh  = (const float*)d_in[7];
    const int*   src   = (const int*)d_in[8];
    const int*   dst   = (const int*)d_in[9];
    float* h = (float*)d_out;

    char* ws = (char*)d_ws;
    size_t off_b = 0;
    auto alloc = [&](size_t bytes) -> void* {
        void* p = ws + off_b;
        off_b = (off_b + bytes + 255) & ~(size_t)255;
        return p;
    };
    int*   cnt    = (int*)  alloc((size_t)N_NODES * 4);
    int*   off    = (int*)  alloc(((size_t)N_NODES + 1) * 4);
    int*   cursor = (int*)  alloc((size_t)N_NODES * 4);
    int*   csr    = (int*)  alloc((size_t)N_EDGES * 4);
    float* Wsd    = (float*)alloc(256 * 256 * 4);
    bf16*  SD     = (bf16*) alloc((size_t)N_NODES * 256 * 2);
    float* cbuf   = (float*)alloc((size_t)N_NODES * 128 * 4);
    bf16*  GI     = (bf16*) alloc((size_t)N_NODES * 384 * 2);
    bf16*  GH     = (bf16*) alloc((size_t)N_NODES * 384 * 2);

    // --- CSR build (graph is fixed across rounds; do once per launch) ---
    hipMemsetAsync(cnt, 0, (size_t)N_NODES * 4, stream);
    hipMemsetAsync(cursor, 0, (size_t)N_NODES * 4, stream);
    deg_kernel<<<(N_EDGES + 255) / 256, 256, 0, stream>>>(dst, cnt, N_EDGES);
    scan_kernel<<<1, 1024, 0, stream>>>(cnt, off, N_NODES);
    fill_csr_kernel<<<(N_EDGES + 255) / 256, 256, 0, stream>>>(src, dst, off, cursor,
                                                               csr, N_EDGES);
    prep_wsd_kernel<<<(256 * 256) / 256, 256, 0, stream>>>(W_msg, Wsd);
    hipMemcpyAsync(h, h0, (size_t)N_NODES * HID * 4, hipMemcpyDeviceToDevice, stream);

    dim3 blk(256);
    dim3 g_sd((N_NODES + TM - 1) / TM, 256 / TN);
    dim3 g_g((N_NODES + TM - 1) / TM, 384 / TN);

    for (int r = 0; r < 2; ++r) {
        // SD = [x|h] @ Wsd^T  (no bias; b_msg folded into agg epilogue)
        gemm_bias_kernel<<<g_sd, blk, 0, stream>>>(x, 128, h, 128, Wsd, nullptr,
                                                   SD, N_NODES, 256);
        agg_kernel<<<(N_NODES * 64 + 255) / 256, 256, 0, stream>>>(
            SD, csr, off, cnt, b_msg, cbuf, N_NODES);
        // GI = [x|c] @ w_ih^T + b_ih
        gemm_bias_kernel<<<g_g, blk, 0, stream>>>(x, 128, cbuf, 128, w_ih, b_ih,
                                                  GI, N_NODES, 384);
        // GH = h @ w_hh^T + b_hh
        gemm_bias_kernel<<<g_g, blk, 0, stream>>>(h, 128, (const float*)nullptr, 0,
                                                  w_hh, b_hh, GH, N_NODES, 384);
        gru_kernel<<<(N_NODES * 128 + 255) / 256, 256, 0, stream>>>(GI, GH, h, N_NODES);
    }
}

// Round 3
// 508.537 us; speedup vs baseline: 7.8644x; 2.5308x over previous
//
#include <hip/hip_runtime.h>
#include <hip/hip_bf16.h>

typedef __hip_bfloat16 bf16;
typedef __bf16 bf16x8 __attribute__((ext_vector_type(8)));
typedef float  f32x4  __attribute__((ext_vector_type(4)));

#define N_NODES 50000
#define N_EDGES 400000
#define HID 128
#define MSG 128

// ---------------------------------------------------------------------------
// MFMA bf16 GEMM:  O[M,J] = A[M,K] @ W[J,K]^T + bias
// A is bf16 with fixed row stride LDA=256. W bf16 [J][K] row-major.
// Block: 256 thr = 4 waves. BM=256 (wave owns 64 rows = 4 m-frags), BN=64
// (4 n-frags). W-tile (BN x K) staged once in LDS, chunked [K/8][64][8]
// -> 2-way-bank-conflict-free ds_read_b128. No barrier in K loop.
// ---------------------------------------------------------------------------
#define LDA 256

template <int K>
__global__ __launch_bounds__(256)
void gemm_mfma_kernel(const bf16* __restrict__ A,
                      const bf16* __restrict__ W,
                      const float* __restrict__ bias,   // or nullptr
                      bf16* __restrict__ O, int M, int J) {
    constexpr int KC = K >> 3;               // 16B chunks along K
    __shared__ bf16 Ws[64 * K];              // [kc][j][8]

    const int tid = threadIdx.x;
    const int bm = blockIdx.x * 256;
    const int bn = blockIdx.y * 64;

    // stage W tile: consecutive threads read consecutive k-chunks (coalesced)
    for (int c = tid; c < 64 * KC; c += 256) {
        int j  = c / KC;
        int kc = c % KC;
        const float4 v = *reinterpret_cast<const float4*>(
            W + (size_t)(bn + j) * K + kc * 8);
        *reinterpret_cast<float4*>(&Ws[(kc * 64 + j) * 8]) = v;
    }
    __syncthreads();

    const int w    = tid >> 6;
    const int lane = tid & 63;
    const int lr   = lane & 15;   // row-in-frag (A) / col-in-frag (B, C/D)
    const int kg   = lane >> 4;   // k-group (8 elems each)
    const int mbase = bm + w * 64;

    // per-frag A row pointers (clamped; OOB frags discarded at store)
    const bf16* Arow[4];
    #pragma unroll
    for (int fm = 0; fm < 4; ++fm) {
        int m = mbase + fm * 16 + lr;
        if (m >= M) m = M - 1;
        Arow[fm] = A + (size_t)m * LDA + kg * 8;
    }

    f32x4 acc[4][4] = {};

    #pragma unroll
    for (int k0 = 0; k0 < K; k0 += 32) {
        bf16x8 a[4];
        #pragma unroll
        for (int fm = 0; fm < 4; ++fm)
            a[fm] = *reinterpret_cast<const bf16x8*>(Arow[fm] + k0);
        const int kcb = (k0 >> 3) + kg;
        #pragma unroll
        for (int fn = 0; fn < 4; ++fn) {
            bf16x8 b = *reinterpret_cast<const bf16x8*>(
                &Ws[(kcb * 64 + fn * 16 + lr) * 8]);
            #pragma unroll
            for (int fm = 0; fm < 4; ++fm)
                acc[fm][fn] = __builtin_amdgcn_mfma_f32_16x16x32_bf16(
                    a[fm], b, acc[fm][fn], 0, 0, 0);
        }
    }

    // epilogue: C/D layout col=lane&15, row=(lane>>4)*4+reg  [m89-verified]
    #pragma unroll
    for (int fn = 0; fn < 4; ++fn) {
        int col = bn + fn * 16 + lr;
        float bv = bias ? bias[col] : 0.0f;
        #pragma unroll
        for (int fm = 0; fm < 4; ++fm) {
            int row0 = mbase + fm * 16 + kg * 4;
            #pragma unroll
            for (int r = 0; r < 4; ++r) {
                int row = row0 + r;
                if (row < M)
                    O[(size_t)row * J + col] = __float2bfloat16(acc[fm][fn][r] + bv);
            }
        }
    }
}

// ---------------------------------------------------------------------------
// Weight prep: Wsd[256][256] bf16. rows 0..127 = S weights (W_msg cols 0..255),
// rows 128..255 = D weights (W_msg cols 256..511).
// ---------------------------------------------------------------------------
__global__ __launch_bounds__(256)
void prep_wsd_kernel(const float* __restrict__ W_msg, bf16* __restrict__ Wsd) {
    int gid = blockIdx.x * 256 + threadIdx.x;   // 256*256 total
    int jj = gid >> 8;
    int k  = gid & 255;
    float v = (jj < 128) ? W_msg[jj * 512 + k]
                         : W_msg[(jj - 128) * 512 + 256 + k];
    Wsd[jj * 256 + k] = __float2bfloat16(v);
}

// generic f32 -> bf16 flat convert
__global__ __launch_bounds__(256)
void conv_flat_kernel(const float* __restrict__ in, bf16* __restrict__ out, int n) {
    int i = blockIdx.x * 256 + threadIdx.x;
    if (i < n) out[i] = __float2bfloat16(in[i]);
}

// x (f32 [N,128]) -> XH[:, :128] and XC[:, :128] (bf16, row stride 256)
__global__ __launch_bounds__(256)
void conv_x_kernel(const float* __restrict__ x, bf16* __restrict__ XH,
                   bf16* __restrict__ XC, int N) {
    int gid = blockIdx.x * 256 + threadIdx.x;
    int v = gid >> 7, j = gid & 127;
    if (v >= N) return;
    bf16 b = __float2bfloat16(x[gid]);
    XH[(size_t)v * 256 + j] = b;
    XC[(size_t)v * 256 + j] = b;
}

// h0 (f32) -> XH[:, 128:] bf16
__global__ __launch_bounds__(256)
void conv_h_kernel(const float* __restrict__ h0, bf16* __restrict__ XH, int N) {
    int gid = blockIdx.x * 256 + threadIdx.x;
    int v = gid >> 7, j = gid & 127;
    if (v >= N) return;
    XH[(size_t)v * 256 + 128 + j] = __float2bfloat16(h0[gid]);
}

// ---------------------------------------------------------------------------
// CSR build (graph fixed across rounds)
// ---------------------------------------------------------------------------
__global__ __launch_bounds__(256)
void deg_kernel(const int* __restrict__ dst, int* __restrict__ cnt, int E) {
    int e = blockIdx.x * 256 + threadIdx.x;
    if (e < E) atomicAdd(&cnt[dst[e]], 1);
}

__global__ __launch_bounds__(1024)
void scan_kernel(const int* __restrict__ cnt, int* __restrict__ off, int N) {
    __shared__ int psum[1024];
    const int t = threadIdx.x;
    const int chunk = (N + 1023) / 1024;
    const int lo = t * chunk;
    const int hi = min(lo + chunk, N);
    int s = 0;
    for (int i = lo; i < hi; ++i) s += cnt[i];
    psum[t] = s;
    __syncthreads();
    for (int d = 1; d < 1024; d <<= 1) {
        int v = (t >= d) ? psum[t - d] : 0;
        __syncthreads();
        psum[t] += v;
        __syncthreads();
    }
    int run = (t > 0) ? psum[t - 1] : 0;
    for (int i = lo; i < hi; ++i) {
        off[i] = run;
        run += cnt[i];
    }
    if (t == 1023) off[N] = run;
}

__global__ __launch_bounds__(256)
void fill_csr_kernel(const int* __restrict__ src, const int* __restrict__ dst,
                     const int* __restrict__ off, int* __restrict__ cursor,
                     int* __restrict__ csr, int E) {
    int e = blockIdx.x * 256 + threadIdx.x;
    if (e >= E) return;
    int d = dst[e];
    int pos = atomicAdd(&cursor[d], 1);
    csr[off[d] + pos] = src[e];
}

// ---------------------------------------------------------------------------
// Gather-aggregate + fused mean/D/bias epilogue -> XC[:, 128:] (bf16)
// One wave per node; lane i owns features {2i, 2i+1}.
// ---------------------------------------------------------------------------
__global__ __launch_bounds__(256)
void agg_kernel(const bf16* __restrict__ SD, const int* __restrict__ csr,
                const int* __restrict__ off, const int* __restrict__ cnt,
                const float* __restrict__ b_msg, bf16* __restrict__ XC, int N) {
    const int v    = (blockIdx.x * 256 + threadIdx.x) >> 6;
    const int lane = threadIdx.x & 63;
    if (v >= N) return;
    const int deg  = cnt[v];
    const int base = off[v];

    float accx0 = 0.f, accy0 = 0.f, accx1 = 0.f, accy1 = 0.f;
    int k = 0;
    for (; k + 1 < deg; k += 2) {
        int s0 = csr[base + k];
        int s1 = csr[base + k + 1];
        unsigned u0 = *reinterpret_cast<const unsigned*>(SD + (size_t)s0 * 256 + lane * 2);
        unsigned u1 = *reinterpret_cast<const unsigned*>(SD + (size_t)s1 * 256 + lane * 2);
        accx0 += __uint_as_float(u0 << 16);
        accy0 += __uint_as_float(u0 & 0xffff0000u);
        accx1 += __uint_as_float(u1 << 16);
        accy1 += __uint_as_float(u1 & 0xffff0000u);
    }
    if (k < deg) {
        int s0 = csr[base + k];
        unsigned u0 = *reinterpret_cast<const unsigned*>(SD + (size_t)s0 * 256 + lane * 2);
        accx0 += __uint_as_float(u0 << 16);
        accy0 += __uint_as_float(u0 & 0xffff0000u);
    }

    float ox = 0.f, oy = 0.f;
    if (deg > 0) {
        unsigned ud = *reinterpret_cast<const unsigned*>(SD + (size_t)v * 256 + 128 + lane * 2);
        float inv = 1.0f / (float)deg;
        const float2 bm = *reinterpret_cast<const float2*>(b_msg + lane * 2);
        ox = (accx0 + accx1) * inv + __uint_as_float(ud << 16)         + bm.x;
        oy = (accy0 + accy1) * inv + __uint_as_float(ud & 0xffff0000u) + bm.y;
    }
    __hip_bfloat162 o2;
    o2.x = __float2bfloat16(ox);
    o2.y = __float2bfloat16(oy);
    *reinterpret_cast<__hip_bfloat162*>(XC + (size_t)v * 256 + 128 + lane * 2) = o2;
}

// ---------------------------------------------------------------------------
// GRU gates: h = (1-z)*n + z*h ; also write bf16 h into XH[:, 128:]
// ---------------------------------------------------------------------------
__global__ __launch_bounds__(256)
void gru_kernel(const bf16* __restrict__ GI, const bf16* __restrict__ GH,
                float* __restrict__ h, bf16* __restrict__ XH, int N) {
    int gid = blockIdx.x * 256 + threadIdx.x;
    int v = gid >> 7;
    int j = gid & 127;
    if (v >= N) return;
    size_t base = (size_t)v * 384;
    float ir = __bfloat162float(GI[base + j]);
    float iz = __bfloat162float(GI[base + 128 + j]);
    float in_ = __bfloat162float(GI[base + 256 + j]);
    float hr = __bfloat162float(GH[base + j]);
    float hz = __bfloat162float(GH[base + 128 + j]);
    float hn = __bfloat162float(GH[base + 256 + j]);
    float r = 1.0f / (1.0f + expf(-(ir + hr)));
    float z = 1.0f / (1.0f + expf(-(iz + hz)));
    float n = tanhf(in_ + r * hn);
    size_t hi = (size_t)v * 128 + j;
    float hv = (1.0f - z) * n + z * h[hi];
    h[hi] = hv;
    XH[(size_t)v * 256 + 128 + j] = __float2bfloat16(hv);
}

// ---------------------------------------------------------------------------
extern "C" void kernel_launch(void* const* d_in, const int* in_sizes, int n_in,
                              void* d_out, int out_size, void* d_ws, size_t ws_size,
                              hipStream_t stream) {
    const float* x     = (const float*)d_in[0];
    const float* h0    = (const float*)d_in[1];
    const float* W_msg = (const float*)d_in[2];
    const float* b_msg = (const float*)d_in[3];
    const float* w_ih  = (const float*)d_in[4];
    const float* w_hh  = (const float*)d_in[5];
    const float* b_ih  = (const float*)d_in[6];
    const float* b_hh  = (const float*)d_in[7];
    const int*   src   = (const int*)d_in[8];
    const int*   dst   = (const int*)d_in[9];
    float* h = (float*)d_out;

    char* ws = (char*)d_ws;
    size_t off_b = 0;
    auto alloc = [&](size_t bytes) -> void* {
        void* p = ws + off_b;
        off_b = (off_b + bytes + 255) & ~(size_t)255;
        return p;
    };
    int*  cnt    = (int*) alloc((size_t)N_NODES * 4);
    int*  off    = (int*) alloc(((size_t)N_NODES + 1) * 4);
    int*  cursor = (int*) alloc((size_t)N_NODES * 4);
    int*  csr    = (int*) alloc((size_t)N_EDGES * 4);
    bf16* Wsd_b  = (bf16*)alloc(256 * 256 * 2);
    bf16* wih_b  = (bf16*)alloc(384 * 256 * 2);
    bf16* whh_b  = (bf16*)alloc(384 * 128 * 2);
    bf16* XH     = (bf16*)alloc((size_t)N_NODES * 256 * 2);
    bf16* XC     = (bf16*)alloc((size_t)N_NODES * 256 * 2);
    bf16* GI     = (bf16*)alloc((size_t)N_NODES * 384 * 2);
    bf16* GH     = (bf16*)alloc((size_t)N_NODES * 384 * 2);
    bf16* SD     = GH;   // SD dead after agg; GH written later -> alias

    // --- one-time per launch: CSR + conversions ---
    hipMemsetAsync(cnt, 0, (size_t)N_NODES * 4, stream);
    hipMemsetAsync(cursor, 0, (size_t)N_NODES * 4, stream);
    deg_kernel<<<(N_EDGES + 255) / 256, 256, 0, stream>>>(dst, cnt, N_EDGES);
    scan_kernel<<<1, 1024, 0, stream>>>(cnt, off, N_NODES);
    fill_csr_kernel<<<(N_EDGES + 255) / 256, 256, 0, stream>>>(src, dst, off, cursor,
                                                               csr, N_EDGES);
    prep_wsd_kernel<<<256, 256, 0, stream>>>(W_msg, Wsd_b);
    conv_flat_kernel<<<(384 * 256 + 255) / 256, 256, 0, stream>>>(w_ih, wih_b, 384 * 256);
    conv_flat_kernel<<<(384 * 128 + 255) / 256, 256, 0, stream>>>(w_hh, whh_b, 384 * 128);
    conv_x_kernel<<<(N_NODES * 128 + 255) / 256, 256, 0, stream>>>(x, XH, XC, N_NODES);
    conv_h_kernel<<<(N_NODES * 128 + 255) / 256, 256, 0, stream>>>(h0, XH, N_NODES);
    hipMemcpyAsync(h, h0, (size_t)N_NODES * HID * 4, hipMemcpyDeviceToDevice, stream);

    const int MB = (N_NODES + 255) / 256;   // 196
    dim3 blk(256);

    for (int r = 0; r < 2; ++r) {
        // SD = XH @ Wsd^T
        gemm_mfma_kernel<256><<<dim3(MB, 4), blk, 0, stream>>>(
            XH, Wsd_b, nullptr, SD, N_NODES, 256);
        // c -> XC[:,128:]
        agg_kernel<<<(N_NODES * 64 + 255) / 256, blk, 0, stream>>>(
            SD, csr, off, cnt, b_msg, XC, N_NODES);
        // GI = XC @ w_ih^T + b_ih
        gemm_mfma_kernel<256><<<dim3(MB, 6), blk, 0, stream>>>(
            XC, wih_b, b_ih, GI, N_NODES, 384);
        // GH = h @ w_hh^T + b_hh   (A = XH[:,128:], ldA=256)
        gemm_mfma_kernel<128><<<dim3(MB, 6), blk, 0, stream>>>(
            XH + 128, whh_b, b_hh, GH, N_NODES, 384);
        gru_kernel<<<(N_NODES * 128 + 255) / 256, blk, 0, stream>>>(
            GI, GH, h, XH, N_NODES);
    }
}

// Round 4
// 413.325 us; speedup vs baseline: 9.6759x; 1.2304x over previous
//
#include <hip/hip_runtime.h>
#include <hip/hip_bf16.h>

typedef __hip_bfloat16 bf16;
typedef __bf16 bf16x8 __attribute__((ext_vector_type(8)));
typedef float  f32x4  __attribute__((ext_vector_type(4)));

#define N_NODES 50000
#define N_EDGES 400000
#define HID 128
#define MSG 128

// ---------------------------------------------------------------------------
// MFMA bf16 GEMM:  O[M,J] = A[M,K] @ W[J,K]^T + bias
// A is bf16 with fixed row stride LDA=256. W bf16 [J][K] row-major.
// Block: 256 thr = 4 waves. BM=256 (wave owns 64 rows = 4 m-frags), BN=64
// (4 n-frags). W-tile (BN x K) staged once in LDS, chunked [K/8][64][8]
// -> 2-way-bank-conflict-free ds_read_b128. No barrier in K loop.
// ---------------------------------------------------------------------------
#define LDA 256

template <int K>
__global__ __launch_bounds__(256)
void gemm_mfma_kernel(const bf16* __restrict__ A,
                      const bf16* __restrict__ W,
                      const float* __restrict__ bias,   // or nullptr
                      bf16* __restrict__ O, int M, int J) {
    constexpr int KC = K >> 3;               // 16B chunks along K
    __shared__ bf16 Ws[64 * K];              // [kc][j][8]

    const int tid = threadIdx.x;
    const int bm = blockIdx.x * 256;
    const int bn = blockIdx.y * 64;

    // stage W tile: consecutive threads read consecutive k-chunks (coalesced)
    for (int c = tid; c < 64 * KC; c += 256) {
        int j  = c / KC;
        int kc = c % KC;
        const float4 v = *reinterpret_cast<const float4*>(
            W + (size_t)(bn + j) * K + kc * 8);
        *reinterpret_cast<float4*>(&Ws[(kc * 64 + j) * 8]) = v;
    }
    __syncthreads();

    const int w    = tid >> 6;
    const int lane = tid & 63;
    const int lr   = lane & 15;   // row-in-frag (A) / col-in-frag (B, C/D)
    const int kg   = lane >> 4;   // k-group (8 elems each)
    const int mbase = bm + w * 64;

    // per-frag A row pointers (clamped; OOB frags discarded at store)
    const bf16* Arow[4];
    #pragma unroll
    for (int fm = 0; fm < 4; ++fm) {
        int m = mbase + fm * 16 + lr;
        if (m >= M) m = M - 1;
        Arow[fm] = A + (size_t)m * LDA + kg * 8;
    }

    f32x4 acc[4][4] = {};

    #pragma unroll
    for (int k0 = 0; k0 < K; k0 += 32) {
        bf16x8 a[4];
        #pragma unroll
        for (int fm = 0; fm < 4; ++fm)
            a[fm] = *reinterpret_cast<const bf16x8*>(Arow[fm] + k0);
        const int kcb = (k0 >> 3) + kg;
        #pragma unroll
        for (int fn = 0; fn < 4; ++fn) {
            bf16x8 b = *reinterpret_cast<const bf16x8*>(
                &Ws[(kcb * 64 + fn * 16 + lr) * 8]);
            #pragma unroll
            for (int fm = 0; fm < 4; ++fm)
                acc[fm][fn] = __builtin_amdgcn_mfma_f32_16x16x32_bf16(
                    a[fm], b, acc[fm][fn], 0, 0, 0);
        }
    }

    // epilogue: C/D layout col=lane&15, row=(lane>>4)*4+reg  [m89-verified]
    #pragma unroll
    for (int fn = 0; fn < 4; ++fn) {
        int col = bn + fn * 16 + lr;
        float bv = bias ? bias[col] : 0.0f;
        #pragma unroll
        for (int fm = 0; fm < 4; ++fm) {
            int row0 = mbase + fm * 16 + kg * 4;
            #pragma unroll
            for (int r = 0; r < 4; ++r) {
                int row = row0 + r;
                if (row < M)
                    O[(size_t)row * J + col] = __float2bfloat16(acc[fm][fn][r] + bv);
            }
        }
    }
}

// ---------------------------------------------------------------------------
// Weight prep: Wsd[256][256] bf16. rows 0..127 = S weights (W_msg cols 0..255),
// rows 128..255 = D weights (W_msg cols 256..511).
// ---------------------------------------------------------------------------
__global__ __launch_bounds__(256)
void prep_wsd_kernel(const float* __restrict__ W_msg, bf16* __restrict__ Wsd) {
    int gid = blockIdx.x * 256 + threadIdx.x;   // 256*256 total
    int jj = gid >> 8;
    int k  = gid & 255;
    float v = (jj < 128) ? W_msg[jj * 512 + k]
                         : W_msg[(jj - 128) * 512 + 256 + k];
    Wsd[jj * 256 + k] = __float2bfloat16(v);
}

// generic f32 -> bf16 flat convert
__global__ __launch_bounds__(256)
void conv_flat_kernel(const float* __restrict__ in, bf16* __restrict__ out, int n) {
    int i = blockIdx.x * 256 + threadIdx.x;
    if (i < n) out[i] = __float2bfloat16(in[i]);
}

// x -> XH[:, :128] and XC[:, :128]; h0 -> XH[:, 128:]
__global__ __launch_bounds__(256)
void conv_xh_kernel(const float* __restrict__ x, const float* __restrict__ h0,
                    bf16* __restrict__ XH, bf16* __restrict__ XC, int N) {
    int gid = blockIdx.x * 256 + threadIdx.x;
    int v = gid >> 7, j = gid & 127;
    if (v >= N) return;
    bf16 bx = __float2bfloat16(x[gid]);
    XH[(size_t)v * 256 + j] = bx;
    XC[(size_t)v * 256 + j] = bx;
    XH[(size_t)v * 256 + 128 + j] = __float2bfloat16(h0[gid]);
}

// ---------------------------------------------------------------------------
// CSR build (graph fixed across rounds)
// ---------------------------------------------------------------------------
__global__ __launch_bounds__(256)
void deg_kernel(const int* __restrict__ dst, int* __restrict__ cnt, int E) {
    int e = blockIdx.x * 256 + threadIdx.x;
    if (e < E) atomicAdd(&cnt[dst[e]], 1);
}

// Disjoint slab allocation instead of prefix sum: wave-scan + 1 atomic/wave.
__global__ __launch_bounds__(256)
void csr_alloc_kernel(const int* __restrict__ cnt, int* __restrict__ off,
                      int* __restrict__ total, int N) {
    int v = blockIdx.x * 256 + threadIdx.x;
    int lane = threadIdx.x & 63;
    int c = (v < N) ? cnt[v] : 0;
    int s = c;
    #pragma unroll
    for (int d = 1; d < 64; d <<= 1) {
        int t = __shfl_up(s, d, 64);
        if (lane >= d) s += t;
    }
    int wave_total = __shfl(s, 63, 64);
    int base = 0;
    if (lane == 63) base = atomicAdd(total, wave_total);
    base = __shfl(base, 63, 64);
    if (v < N) off[v] = base + s - c;   // exclusive within wave + slab base
}

__global__ __launch_bounds__(256)
void fill_csr_kernel(const int* __restrict__ src, const int* __restrict__ dst,
                     const int* __restrict__ off, int* __restrict__ cursor,
                     int* __restrict__ csr, int E) {
    int e = blockIdx.x * 256 + threadIdx.x;
    if (e >= E) return;
    int d = dst[e];
    int pos = atomicAdd(&cursor[d], 1);
    csr[off[d] + pos] = src[e];
}

// ---------------------------------------------------------------------------
// Gather-aggregate + fused mean/D/bias epilogue -> XC[:, 128:] (bf16)
// One wave per node; lane i owns features {2i, 2i+1}.
// ---------------------------------------------------------------------------
__global__ __launch_bounds__(256)
void agg_kernel(const bf16* __restrict__ SD, const int* __restrict__ csr,
                const int* __restrict__ off, const int* __restrict__ cnt,
                const float* __restrict__ b_msg, bf16* __restrict__ XC, int N) {
    const int v    = (blockIdx.x * 256 + threadIdx.x) >> 6;
    const int lane = threadIdx.x & 63;
    if (v >= N) return;
    const int deg  = cnt[v];
    const int base = off[v];

    float ax[4] = {0.f, 0.f, 0.f, 0.f};
    float ay[4] = {0.f, 0.f, 0.f, 0.f};
    int k = 0;
    for (; k + 3 < deg; k += 4) {
        #pragma unroll
        for (int u = 0; u < 4; ++u) {
            int s0 = csr[base + k + u];
            unsigned q = *reinterpret_cast<const unsigned*>(
                SD + (size_t)s0 * 256 + lane * 2);
            ax[u] += __uint_as_float(q << 16);
            ay[u] += __uint_as_float(q & 0xffff0000u);
        }
    }
    for (; k < deg; ++k) {
        int s0 = csr[base + k];
        unsigned q = *reinterpret_cast<const unsigned*>(
            SD + (size_t)s0 * 256 + lane * 2);
        ax[0] += __uint_as_float(q << 16);
        ay[0] += __uint_as_float(q & 0xffff0000u);
    }

    float ox = 0.f, oy = 0.f;
    if (deg > 0) {
        unsigned ud = *reinterpret_cast<const unsigned*>(SD + (size_t)v * 256 + 128 + lane * 2);
        float inv = 1.0f / (float)deg;
        const float2 bm = *reinterpret_cast<const float2*>(b_msg + lane * 2);
        ox = ((ax[0] + ax[1]) + (ax[2] + ax[3])) * inv + __uint_as_float(ud << 16)         + bm.x;
        oy = ((ay[0] + ay[1]) + (ay[2] + ay[3])) * inv + __uint_as_float(ud & 0xffff0000u) + bm.y;
    }
    __hip_bfloat162 o2;
    o2.x = __float2bfloat16(ox);
    o2.y = __float2bfloat16(oy);
    *reinterpret_cast<__hip_bfloat162*>(XC + (size_t)v * 256 + 128 + lane * 2) = o2;
}

// ---------------------------------------------------------------------------
// GRU gates: h_out = (1-z)*n + z*h_in ; also write bf16 h into XH[:, 128:]
// ---------------------------------------------------------------------------
__global__ __launch_bounds__(256)
void gru_kernel(const bf16* __restrict__ GI, const bf16* __restrict__ GH,
                const float* __restrict__ h_in, float* __restrict__ h_out,
                bf16* __restrict__ XH, int N) {
    int gid = blockIdx.x * 256 + threadIdx.x;
    int v = gid >> 7;
    int j = gid & 127;
    if (v >= N) return;
    size_t base = (size_t)v * 384;
    float ir = __bfloat162float(GI[base + j]);
    float iz = __bfloat162float(GI[base + 128 + j]);
    float in_ = __bfloat162float(GI[base + 256 + j]);
    float hr = __bfloat162float(GH[base + j]);
    float hz = __bfloat162float(GH[base + 128 + j]);
    float hn = __bfloat162float(GH[base + 256 + j]);
    float r = 1.0f / (1.0f + expf(-(ir + hr)));
    float z = 1.0f / (1.0f + expf(-(iz + hz)));
    float n = tanhf(in_ + r * hn);
    float hv = (1.0f - z) * n + z * h_in[gid];
    h_out[gid] = hv;
    XH[(size_t)v * 256 + 128 + j] = __float2bfloat16(hv);
}

// ---------------------------------------------------------------------------
extern "C" void kernel_launch(void* const* d_in, const int* in_sizes, int n_in,
                              void* d_out, int out_size, void* d_ws, size_t ws_size,
                              hipStream_t stream) {
    const float* x     = (const float*)d_in[0];
    const float* h0    = (const float*)d_in[1];
    const float* W_msg = (const float*)d_in[2];
    const float* b_msg = (const float*)d_in[3];
    const float* w_ih  = (const float*)d_in[4];
    const float* w_hh  = (const float*)d_in[5];
    const float* b_ih  = (const float*)d_in[6];
    const float* b_hh  = (const float*)d_in[7];
    const int*   src   = (const int*)d_in[8];
    const int*   dst   = (const int*)d_in[9];
    float* h = (float*)d_out;

    char* ws = (char*)d_ws;
    size_t off_b = 0;
    auto alloc = [&](size_t bytes) -> void* {
        void* p = ws + off_b;
        off_b = (off_b + bytes + 255) & ~(size_t)255;
        return p;
    };
    // meta block: cnt[N] | cursor[N] | total[1]  (one memset covers all)
    int*  meta   = (int*) alloc(((size_t)2 * N_NODES + 64) * 4);
    int*  cnt    = meta;
    int*  cursor = meta + N_NODES;
    int*  total  = meta + 2 * N_NODES;
    int*  off    = (int*) alloc((size_t)N_NODES * 4);
    int*  csr    = (int*) alloc((size_t)N_EDGES * 4);
    bf16* Wsd_b  = (bf16*)alloc(256 * 256 * 2);
    bf16* wih_b  = (bf16*)alloc(384 * 256 * 2);
    bf16* whh_b  = (bf16*)alloc(384 * 128 * 2);
    bf16* XH     = (bf16*)alloc((size_t)N_NODES * 256 * 2);
    bf16* XC     = (bf16*)alloc((size_t)N_NODES * 256 * 2);
    bf16* GI     = (bf16*)alloc((size_t)N_NODES * 384 * 2);
    bf16* GH     = (bf16*)alloc((size_t)N_NODES * 384 * 2);
    bf16* SD     = GH;   // SD dead after agg; GH written later -> alias

    // --- one-time per launch: CSR + conversions ---
    hipMemsetAsync(meta, 0, ((size_t)2 * N_NODES + 64) * 4, stream);
    deg_kernel<<<(N_EDGES + 255) / 256, 256, 0, stream>>>(dst, cnt, N_EDGES);
    csr_alloc_kernel<<<(N_NODES + 255) / 256, 256, 0, stream>>>(cnt, off, total, N_NODES);
    fill_csr_kernel<<<(N_EDGES + 255) / 256, 256, 0, stream>>>(src, dst, off, cursor,
                                                               csr, N_EDGES);
    prep_wsd_kernel<<<256, 256, 0, stream>>>(W_msg, Wsd_b);
    conv_flat_kernel<<<(384 * 256 + 255) / 256, 256, 0, stream>>>(w_ih, wih_b, 384 * 256);
    conv_flat_kernel<<<(384 * 128 + 255) / 256, 256, 0, stream>>>(w_hh, whh_b, 384 * 128);
    conv_xh_kernel<<<(N_NODES * 128 + 255) / 256, 256, 0, stream>>>(x, h0, XH, XC, N_NODES);

    const int MB = (N_NODES + 255) / 256;   // 196
    dim3 blk(256);

    for (int r = 0; r < 2; ++r) {
        // SD = XH @ Wsd^T
        gemm_mfma_kernel<256><<<dim3(MB, 4), blk, 0, stream>>>(
            XH, Wsd_b, nullptr, SD, N_NODES, 256);
        // c -> XC[:,128:]
        agg_kernel<<<(N_NODES * 64 + 255) / 256, blk, 0, stream>>>(
            SD, csr, off, cnt, b_msg, XC, N_NODES);
        // GI = XC @ w_ih^T + b_ih
        gemm_mfma_kernel<256><<<dim3(MB, 6), blk, 0, stream>>>(
            XC, wih_b, b_ih, GI, N_NODES, 384);
        // GH = h @ w_hh^T + b_hh   (A = XH[:,128:], ldA=256)
        gemm_mfma_kernel<128><<<dim3(MB, 6), blk, 0, stream>>>(
            XH + 128, whh_b, b_hh, GH, N_NODES, 384);
        gru_kernel<<<(N_NODES * 128 + 255) / 256, blk, 0, stream>>>(
            GI, GH, (r == 0) ? h0 : h, h, XH, N_NODES);
    }
}

// Round 5
// 342.919 us; speedup vs baseline: 11.6625x; 1.2053x over previous
//
#include <hip/hip_runtime.h>
#include <hip/hip_bf16.h>

typedef __hip_bfloat16 bf16;
typedef __bf16 bf16x8 __attribute__((ext_vector_type(8)));
typedef float  f32x4  __attribute__((ext_vector_type(4)));

#define N_NODES 50000
#define N_EDGES 400000
#define HID 128
#define MSG 128

// ---------------------------------------------------------------------------
// MFMA bf16 GEMM:  O[M,J] = A[M,K] @ W[J,K]^T + bias
// A bf16, row stride LDA=256. W bf16 [J][K] row-major.
// Block: 256 thr = 4 waves. BM=256 (wave owns 64 rows = 4 m-frags), BN=64.
// Ws staged with XOR swizzle (j ^ (kc&7)) -> conflict-free store+read.
// Epilogue: C-tile through LDS (colblk ^ (row>>2)&7 swizzle) -> 128B
// coalesced global stores (fixes partial-line RMW traffic).
// ---------------------------------------------------------------------------
#define LDA 256

template <int K>
__global__ __launch_bounds__(256)
void gemm_mfma_kernel(const bf16* __restrict__ A,
                      const bf16* __restrict__ W,
                      const float* __restrict__ bias,   // or nullptr
                      bf16* __restrict__ O, int M, int J) {
    constexpr int KC = K >> 3;               // 16B chunks along K
    constexpr int LDS_ELEMS = (64 * K > 256 * 64) ? 64 * K : 256 * 64;
    __shared__ bf16 Ws[LDS_ELEMS];           // W tile, then C tile

    const int tid = threadIdx.x;
    const int bm = blockIdx.x * 256;
    const int bn = blockIdx.y * 64;

    // stage W tile: coalesced global read, swizzled LDS store
    for (int c = tid; c < 64 * KC; c += 256) {
        int j  = c / KC;
        int kc = c % KC;
        const float4 v = *reinterpret_cast<const float4*>(
            W + (size_t)(bn + j) * K + kc * 8);
        *reinterpret_cast<float4*>(&Ws[(kc * 64 + (j ^ (kc & 7))) * 8]) = v;
    }
    __syncthreads();

    const int w    = tid >> 6;
    const int lane = tid & 63;
    const int lr   = lane & 15;   // row-in-frag (A) / col-in-frag (B, C/D)
    const int kg   = lane >> 4;   // k-group (8 elems each)
    const int mbase = bm + w * 64;

    // per-frag A row pointers (clamped; OOB rows discarded at store)
    const bf16* Arow[4];
    #pragma unroll
    for (int fm = 0; fm < 4; ++fm) {
        int m = mbase + fm * 16 + lr;
        if (m >= M) m = M - 1;
        Arow[fm] = A + (size_t)m * LDA + kg * 8;
    }

    f32x4 acc[4][4] = {};

    #pragma unroll
    for (int k0 = 0; k0 < K; k0 += 32) {
        bf16x8 a[4];
        #pragma unroll
        for (int fm = 0; fm < 4; ++fm)
            a[fm] = *reinterpret_cast<const bf16x8*>(Arow[fm] + k0);
        const int kcb = (k0 >> 3) + kg;
        #pragma unroll
        for (int fn = 0; fn < 4; ++fn) {
            bf16x8 b = *reinterpret_cast<const bf16x8*>(
                &Ws[(kcb * 64 + ((fn * 16 + lr) ^ (kcb & 7))) * 8]);
            #pragma unroll
            for (int fm = 0; fm < 4; ++fm)
                acc[fm][fn] = __builtin_amdgcn_mfma_f32_16x16x32_bf16(
                    a[fm], b, acc[fm][fn], 0, 0, 0);
        }
    }

    // ---- epilogue: stage C tile in LDS (swizzled), then coalesced write ----
    __syncthreads();                          // Ws reads complete
    // C/D frag layout: col=lane&15, row=(lane>>4)*4+reg  [m89-verified]
    #pragma unroll
    for (int fn = 0; fn < 4; ++fn) {
        int col = fn * 16 + lr;
        float bv = bias ? bias[bn + col] : 0.0f;
        #pragma unroll
        for (int fm = 0; fm < 4; ++fm) {
            int rbase = w * 64 + fm * 16 + kg * 4;
            #pragma unroll
            for (int r = 0; r < 4; ++r) {
                int row = rbase + r;
                int cs = ((((col >> 3) ^ ((row >> 2) & 7))) << 3) | (col & 7);
                Ws[row * 64 + cs] = __float2bfloat16(acc[fm][fn][r] + bv);
            }
        }
    }
    __syncthreads();
    const int colblk = tid & 7;
    const int rbase_o = tid >> 3;             // 0..31
    #pragma unroll
    for (int it = 0; it < 8; ++it) {
        int row = it * 32 + rbase_o;
        int grow = bm + row;
        if (grow < M) {
            int g = (row >> 2) & 7;
            const float4 v = *reinterpret_cast<const float4*>(
                &Ws[row * 64 + ((colblk ^ g) << 3)]);
            *reinterpret_cast<float4*>(O + (size_t)grow * J + bn + colblk * 8) = v;
        }
    }
}

// ---------------------------------------------------------------------------
// Weight prep: Wsd[256][256] bf16. rows 0..127 = S weights (W_msg cols 0..255),
// rows 128..255 = D weights (W_msg cols 256..511).
// ---------------------------------------------------------------------------
__global__ __launch_bounds__(256)
void prep_wsd_kernel(const float* __restrict__ W_msg, bf16* __restrict__ Wsd) {
    int gid = blockIdx.x * 256 + threadIdx.x;   // 256*256 total
    int jj = gid >> 8;
    int k  = gid & 255;
    float v = (jj < 128) ? W_msg[jj * 512 + k]
                         : W_msg[(jj - 128) * 512 + 256 + k];
    Wsd[jj * 256 + k] = __float2bfloat16(v);
}

// generic f32 -> bf16 flat convert
__global__ __launch_bounds__(256)
void conv_flat_kernel(const float* __restrict__ in, bf16* __restrict__ out, int n) {
    int i = blockIdx.x * 256 + threadIdx.x;
    if (i < n) out[i] = __float2bfloat16(in[i]);
}

// x -> XH[:, :128] and XC[:, :128]; h0 -> XH[:, 128:]
__global__ __launch_bounds__(256)
void conv_xh_kernel(const float* __restrict__ x, const float* __restrict__ h0,
                    bf16* __restrict__ XH, bf16* __restrict__ XC, int N) {
    int gid = blockIdx.x * 256 + threadIdx.x;
    int v = gid >> 7, j = gid & 127;
    if (v >= N) return;
    bf16 bx = __float2bfloat16(x[gid]);
    XH[(size_t)v * 256 + j] = bx;
    XC[(size_t)v * 256 + j] = bx;
    XH[(size_t)v * 256 + 128 + j] = __float2bfloat16(h0[gid]);
}

// ---------------------------------------------------------------------------
// CSR build (graph fixed across rounds)
// ---------------------------------------------------------------------------
__global__ __launch_bounds__(256)
void deg_kernel(const int* __restrict__ dst, int* __restrict__ cnt, int E) {
    int e = blockIdx.x * 256 + threadIdx.x;
    if (e < E) atomicAdd(&cnt[dst[e]], 1);
}

// Disjoint slab allocation instead of prefix sum: wave-scan + 1 atomic/wave.
__global__ __launch_bounds__(256)
void csr_alloc_kernel(const int* __restrict__ cnt, int* __restrict__ off,
                      int* __restrict__ total, int N) {
    int v = blockIdx.x * 256 + threadIdx.x;
    int lane = threadIdx.x & 63;
    int c = (v < N) ? cnt[v] : 0;
    int s = c;
    #pragma unroll
    for (int d = 1; d < 64; d <<= 1) {
        int t = __shfl_up(s, d, 64);
        if (lane >= d) s += t;
    }
    int wave_total = __shfl(s, 63, 64);
    int base = 0;
    if (lane == 63) base = atomicAdd(total, wave_total);
    base = __shfl(base, 63, 64);
    if (v < N) off[v] = base + s - c;   // exclusive within wave + slab base
}

__global__ __launch_bounds__(256)
void fill_csr_kernel(const int* __restrict__ src, const int* __restrict__ dst,
                     const int* __restrict__ off, int* __restrict__ cursor,
                     int* __restrict__ csr, int E) {
    int e = blockIdx.x * 256 + threadIdx.x;
    if (e >= E) return;
    int d = dst[e];
    int pos = atomicAdd(&cursor[d], 1);
    csr[off[d] + pos] = src[e];
}

// ---------------------------------------------------------------------------
// Gather-aggregate + fused mean/D/bias epilogue -> XC[:, 128:] (bf16)
// One wave per node; lane i owns features {2i, 2i+1}.
// ---------------------------------------------------------------------------
__global__ __launch_bounds__(256)
void agg_kernel(const bf16* __restrict__ SD, const int* __restrict__ csr,
                const int* __restrict__ off, const int* __restrict__ cnt,
                const float* __restrict__ b_msg, bf16* __restrict__ XC, int N) {
    const int v    = (blockIdx.x * 256 + threadIdx.x) >> 6;
    const int lane = threadIdx.x & 63;
    if (v >= N) return;
    const int deg  = cnt[v];
    const int base = off[v];

    float ax[4] = {0.f, 0.f, 0.f, 0.f};
    float ay[4] = {0.f, 0.f, 0.f, 0.f};
    int k = 0;
    for (; k + 3 < deg; k += 4) {
        #pragma unroll
        for (int u = 0; u < 4; ++u) {
            int s0 = csr[base + k + u];
            unsigned q = *reinterpret_cast<const unsigned*>(
                SD + (size_t)s0 * 256 + lane * 2);
            ax[u] += __uint_as_float(q << 16);
            ay[u] += __uint_as_float(q & 0xffff0000u);
        }
    }
    for (; k < deg; ++k) {
        int s0 = csr[base + k];
        unsigned q = *reinterpret_cast<const unsigned*>(
            SD + (size_t)s0 * 256 + lane * 2);
        ax[0] += __uint_as_float(q << 16);
        ay[0] += __uint_as_float(q & 0xffff0000u);
    }

    float ox = 0.f, oy = 0.f;
    if (deg > 0) {
        unsigned ud = *reinterpret_cast<const unsigned*>(SD + (size_t)v * 256 + 128 + lane * 2);
        float inv = 1.0f / (float)deg;
        const float2 bm = *reinterpret_cast<const float2*>(b_msg + lane * 2);
        ox = ((ax[0] + ax[1]) + (ax[2] + ax[3])) * inv + __uint_as_float(ud << 16)         + bm.x;
        oy = ((ay[0] + ay[1]) + (ay[2] + ay[3])) * inv + __uint_as_float(ud & 0xffff0000u) + bm.y;
    }
    __hip_bfloat162 o2;
    o2.x = __float2bfloat16(ox);
    o2.y = __float2bfloat16(oy);
    *reinterpret_cast<__hip_bfloat162*>(XC + (size_t)v * 256 + 128 + lane * 2) = o2;
}

// ---------------------------------------------------------------------------
// GRU gates: h_out = (1-z)*n + z*h_in ; also write bf16 h into XH[:, 128:]
// ---------------------------------------------------------------------------
__global__ __launch_bounds__(256)
void gru_kernel(const bf16* __restrict__ GI, const bf16* __restrict__ GH,
                const float* __restrict__ h_in, float* __restrict__ h_out,
                bf16* __restrict__ XH, int N) {
    int gid = blockIdx.x * 256 + threadIdx.x;
    int v = gid >> 7;
    int j = gid & 127;
    if (v >= N) return;
    size_t base = (size_t)v * 384;
    float ir = __bfloat162float(GI[base + j]);
    float iz = __bfloat162float(GI[base + 128 + j]);
    float in_ = __bfloat162float(GI[base + 256 + j]);
    float hr = __bfloat162float(GH[base + j]);
    float hz = __bfloat162float(GH[base + 128 + j]);
    float hn = __bfloat162float(GH[base + 256 + j]);
    float r = 1.0f / (1.0f + expf(-(ir + hr)));
    float z = 1.0f / (1.0f + expf(-(iz + hz)));
    float n = tanhf(in_ + r * hn);
    float hv = (1.0f - z) * n + z * h_in[gid];
    h_out[gid] = hv;
    XH[(size_t)v * 256 + 128 + j] = __float2bfloat16(hv);
}

// ---------------------------------------------------------------------------
extern "C" void kernel_launch(void* const* d_in, const int* in_sizes, int n_in,
                              void* d_out, int out_size, void* d_ws, size_t ws_size,
                              hipStream_t stream) {
    const float* x     = (const float*)d_in[0];
    const float* h0    = (const float*)d_in[1];
    const float* W_msg = (const float*)d_in[2];
    const float* b_msg = (const float*)d_in[3];
    const float* w_ih  = (const float*)d_in[4];
    const float* w_hh  = (const float*)d_in[5];
    const float* b_ih  = (const float*)d_in[6];
    const float* b_hh  = (const float*)d_in[7];
    const int*   src   = (const int*)d_in[8];
    const int*   dst   = (const int*)d_in[9];
    float* h = (float*)d_out;

    char* ws = (char*)d_ws;
    size_t off_b = 0;
    auto alloc = [&](size_t bytes) -> void* {
        void* p = ws + off_b;
        off_b = (off_b + bytes + 255) & ~(size_t)255;
        return p;
    };
    // meta block: cnt[N] | cursor[N] | total[1]  (one memset covers all)
    int*  meta   = (int*) alloc(((size_t)2 * N_NODES + 64) * 4);
    int*  cnt    = meta;
    int*  cursor = meta + N_NODES;
    int*  total  = meta + 2 * N_NODES;
    int*  off    = (int*) alloc((size_t)N_NODES * 4);
    int*  csr    = (int*) alloc((size_t)N_EDGES * 4);
    bf16* Wsd_b  = (bf16*)alloc(256 * 256 * 2);
    bf16* wih_b  = (bf16*)alloc(384 * 256 * 2);
    bf16* whh_b  = (bf16*)alloc(384 * 128 * 2);
    bf16* XH     = (bf16*)alloc((size_t)N_NODES * 256 * 2);
    bf16* XC     = (bf16*)alloc((size_t)N_NODES * 256 * 2);
    bf16* GI     = (bf16*)alloc((size_t)N_NODES * 384 * 2);
    bf16* GH     = (bf16*)alloc((size_t)N_NODES * 384 * 2);
    bf16* SD     = GH;   // SD dead after agg; GH written later -> alias

    // --- one-time per launch: CSR + conversions ---
    hipMemsetAsync(meta, 0, ((size_t)2 * N_NODES + 64) * 4, stream);
    deg_kernel<<<(N_EDGES + 255) / 256, 256, 0, stream>>>(dst, cnt, N_EDGES);
    csr_alloc_kernel<<<(N_NODES + 255) / 256, 256, 0, stream>>>(cnt, off, total, N_NODES);
    fill_csr_kernel<<<(N_EDGES + 255) / 256, 256, 0, stream>>>(src, dst, off, cursor,
                                                               csr, N_EDGES);
    prep_wsd_kernel<<<256, 256, 0, stream>>>(W_msg, Wsd_b);
    conv_flat_kernel<<<(384 * 256 + 255) / 256, 256, 0, stream>>>(w_ih, wih_b, 384 * 256);
    conv_flat_kernel<<<(384 * 128 + 255) / 256, 256, 0, stream>>>(w_hh, whh_b, 384 * 128);
    conv_xh_kernel<<<(N_NODES * 128 + 255) / 256, 256, 0, stream>>>(x, h0, XH, XC, N_NODES);

    const int MB = (N_NODES + 255) / 256;   // 196
    dim3 blk(256);

    for (int r = 0; r < 2; ++r) {
        // SD = XH @ Wsd^T
        gemm_mfma_kernel<256><<<dim3(MB, 4), blk, 0, stream>>>(
            XH, Wsd_b, nullptr, SD, N_NODES, 256);
        // c -> XC[:,128:]
        agg_kernel<<<(N_NODES * 64 + 255) / 256, blk, 0, stream>>>(
            SD, csr, off, cnt, b_msg, XC, N_NODES);
        // GI = XC @ w_ih^T + b_ih
        gemm_mfma_kernel<256><<<dim3(MB, 6), blk, 0, stream>>>(
            XC, wih_b, b_ih, GI, N_NODES, 384);
        // GH = h @ w_hh^T + b_hh   (A = XH[:,128:], ldA=256)
        gemm_mfma_kernel<128><<<dim3(MB, 6), blk, 0, stream>>>(
            XH + 128, whh_b, b_hh, GH, N_NODES, 384);
        gru_kernel<<<(N_NODES * 128 + 255) / 256, blk, 0, stream>>>(
            GI, GH, (r == 0) ? h0 : h, h, XH, N_NODES);
    }
}

// Round 6
// 336.150 us; speedup vs baseline: 11.8974x; 1.0201x over previous
//
#include <hip/hip_runtime.h>
#include <hip/hip_bf16.h>

typedef __hip_bfloat16 bf16;
typedef __bf16 bf16x8 __attribute__((ext_vector_type(8)));
typedef float  f32x4  __attribute__((ext_vector_type(4)));

#define N_NODES 50000
#define N_EDGES 400000
#define HID 128
#define MSG 128

// ---------------------------------------------------------------------------
// MFMA bf16 GEMM:  O[M,J] = A[M,K] @ W[J,K]^T + bias
// A bf16, row stride LDA=256. W bf16 [J,K] row-major.
// 256 thr = 4 waves, BM=256, BN=64. Ws XOR-swizzled; epilogue via LDS for
// coalesced 128B stores. (proven R5 structure)
// ---------------------------------------------------------------------------
#define LDA 256

template <int K>
__global__ __launch_bounds__(256)
void gemm_mfma_kernel(const bf16* __restrict__ A,
                      const bf16* __restrict__ W,
                      const float* __restrict__ bias,   // or nullptr
                      bf16* __restrict__ O, int M, int J) {
    constexpr int KC = K >> 3;               // 16B chunks along K
    constexpr int LDS_ELEMS = (64 * K > 256 * 64) ? 64 * K : 256 * 64;
    __shared__ bf16 Ws[LDS_ELEMS];           // W tile, then C tile

    const int tid = threadIdx.x;
    const int bm = blockIdx.x * 256;
    const int bn = blockIdx.y * 64;

    for (int c = tid; c < 64 * KC; c += 256) {
        int j  = c / KC;
        int kc = c % KC;
        const float4 v = *reinterpret_cast<const float4*>(
            W + (size_t)(bn + j) * K + kc * 8);
        *reinterpret_cast<float4*>(&Ws[(kc * 64 + (j ^ (kc & 7))) * 8]) = v;
    }
    __syncthreads();

    const int w    = tid >> 6;
    const int lane = tid & 63;
    const int lr   = lane & 15;
    const int kg   = lane >> 4;
    const int mbase = bm + w * 64;

    const bf16* Arow[4];
    #pragma unroll
    for (int fm = 0; fm < 4; ++fm) {
        int m = mbase + fm * 16 + lr;
        if (m >= M) m = M - 1;
        Arow[fm] = A + (size_t)m * LDA + kg * 8;
    }

    f32x4 acc[4][4] = {};

    #pragma unroll
    for (int k0 = 0; k0 < K; k0 += 32) {
        bf16x8 a[4];
        #pragma unroll
        for (int fm = 0; fm < 4; ++fm)
            a[fm] = *reinterpret_cast<const bf16x8*>(Arow[fm] + k0);
        const int kcb = (k0 >> 3) + kg;
        #pragma unroll
        for (int fn = 0; fn < 4; ++fn) {
            bf16x8 b = *reinterpret_cast<const bf16x8*>(
                &Ws[(kcb * 64 + ((fn * 16 + lr) ^ (kcb & 7))) * 8]);
            #pragma unroll
            for (int fm = 0; fm < 4; ++fm)
                acc[fm][fn] = __builtin_amdgcn_mfma_f32_16x16x32_bf16(
                    a[fm], b, acc[fm][fn], 0, 0, 0);
        }
    }

    __syncthreads();
    #pragma unroll
    for (int fn = 0; fn < 4; ++fn) {
        int col = fn * 16 + lr;
        float bv = bias ? bias[bn + col] : 0.0f;
        #pragma unroll
        for (int fm = 0; fm < 4; ++fm) {
            int rbase = w * 64 + fm * 16 + kg * 4;
            #pragma unroll
            for (int r = 0; r < 4; ++r) {
                int row = rbase + r;
                int cs = ((((col >> 3) ^ ((row >> 2) & 7))) << 3) | (col & 7);
                Ws[row * 64 + cs] = __float2bfloat16(acc[fm][fn][r] + bv);
            }
        }
    }
    __syncthreads();
    const int colblk = tid & 7;
    const int rbase_o = tid >> 3;
    #pragma unroll
    for (int it = 0; it < 8; ++it) {
        int row = it * 32 + rbase_o;
        int grow = bm + row;
        if (grow < M) {
            int g = (row >> 2) & 7;
            const float4 v = *reinterpret_cast<const float4*>(
                &Ws[row * 64 + ((colblk ^ g) << 3)]);
            *reinterpret_cast<float4*>(O + (size_t)grow * J + bn + colblk * 8) = v;
        }
    }
}

// ---------------------------------------------------------------------------
// Fused GH-GEMM + GRU.  Block: 256 thr = 4 waves, BM=64 (16 rows/wave),
// full J=384 in-block as 24 n-frags -> gate triplet (r,z,n) is LANE-LOCAL
// (frags fn, fn+8, fn+16 share col=fn*16+lr).
// GH = h_bf16 @ w_hh^T (+b_hh in epilogue); gates combined with GI (global
// scalar reads) and h_in; writes h (f32 if FINAL else bf16 into XH h-half).
// w_hh staged per-gate: 3 chunks of 128 cols x K=128 (32KB, XOR-swizzled).
// ---------------------------------------------------------------------------
__device__ __forceinline__ float fast_sigmoid(float x) {
    return 1.0f / (1.0f + __expf(-x));
}
__device__ __forceinline__ float fast_tanh(float x) {
    float e = __expf(-2.0f * fabsf(x));
    float t = (1.0f - e) / (1.0f + e);
    return copysignf(t, x);
}

template <int FINAL>
__global__ __launch_bounds__(256)
void ghgru_kernel(const bf16* __restrict__ XH,      // [N,256], h in cols 128..255
                  const bf16* __restrict__ whh,     // [384,128] bf16
                  const float* __restrict__ b_hh,
                  const bf16* __restrict__ GI,      // [N,384] bf16 (has b_ih)
                  const float* __restrict__ h0,     // f32 h_in (round 0 only)
                  float* __restrict__ h_out,        // f32 out (FINAL only)
                  bf16* __restrict__ XHw,           // XH h-half write (non-final)
                  int M) {
    __shared__ bf16 Ws[128 * 128];     // one gate chunk [kc][col][8], swizzled

    const int tid  = threadIdx.x;
    const int w    = tid >> 6;
    const int lane = tid & 63;
    const int lr   = lane & 15;
    const int kg   = lane >> 4;
    const int mbase = blockIdx.x * 64 + w * 16;

    // A rows (h half of XH), clamped
    int arow = mbase + lr;
    if (arow >= M) arow = M - 1;
    const bf16* Aptr = XH + (size_t)arow * 256 + 128 + kg * 8;
    bf16x8 a[4];
    #pragma unroll
    for (int k0 = 0; k0 < 4; ++k0)
        a[k0] = *reinterpret_cast<const bf16x8*>(Aptr + k0 * 32);

    f32x4 acc[24];
    #pragma unroll
    for (int i = 0; i < 24; ++i) acc[i] = f32x4{0.f, 0.f, 0.f, 0.f};

    #pragma unroll
    for (int g = 0; g < 3; ++g) {
        __syncthreads();   // previous chunk reads done
        // stage gate-g weights: cols g*128..g*128+127, K=128 -> [16 kc][128 col][8]
        for (int c = tid; c < 128 * 16; c += 256) {
            int col = c >> 4;
            int kc  = c & 15;
            const float4 v = *reinterpret_cast<const float4*>(
                whh + (size_t)(g * 128 + col) * 128 + kc * 8);
            *reinterpret_cast<float4*>(&Ws[(kc * 128 + (col ^ (kc & 7))) * 8]) = v;
        }
        __syncthreads();
        #pragma unroll
        for (int fl = 0; fl < 8; ++fl) {
            #pragma unroll
            for (int k0 = 0; k0 < 4; ++k0) {
                const int kcb = k0 * 4 + kg;
                bf16x8 b = *reinterpret_cast<const bf16x8*>(
                    &Ws[(kcb * 128 + ((fl * 16 + lr) ^ (kcb & 7))) * 8]);
                acc[g * 8 + fl] = __builtin_amdgcn_mfma_f32_16x16x32_bf16(
                    a[k0], b, acc[g * 8 + fl], 0, 0, 0);
            }
        }
    }

    // ---- fused GRU epilogue: triplet lane-local ----
    const unsigned short* gi16 = reinterpret_cast<const unsigned short*>(GI);
    #pragma unroll
    for (int fl = 0; fl < 8; ++fl) {
        const int col = fl * 16 + lr;
        const float bhr = b_hh[col];
        const float bhz = b_hh[col + 128];
        const float bhn = b_hh[col + 256];
        #pragma unroll
        for (int r = 0; r < 4; ++r) {
            const int row = mbase + kg * 4 + r;
            if (row >= M) continue;
            const size_t gbase = (size_t)row * 384 + col;
            float gir = __uint_as_float((unsigned)gi16[gbase] << 16);
            float giz = __uint_as_float((unsigned)gi16[gbase + 128] << 16);
            float gin = __uint_as_float((unsigned)gi16[gbase + 256] << 16);
            float ghr = acc[fl][r] + bhr;
            float ghz = acc[fl + 8][r] + bhz;
            float ghn = acc[fl + 16][r] + bhn;
            float rr = fast_sigmoid(gir + ghr);
            float zz = fast_sigmoid(giz + ghz);
            float nn = fast_tanh(gin + rr * ghn);
            float hin;
            if (FINAL) {
                hin = __bfloat162float(XH[(size_t)row * 256 + 128 + col]);
            } else {
                hin = h0[(size_t)row * 128 + col];
            }
            float hv = (1.0f - zz) * nn + zz * hin;
            if (FINAL) {
                h_out[(size_t)row * 128 + col] = hv;
            } else {
                XHw[(size_t)row * 256 + 128 + col] = __float2bfloat16(hv);
            }
        }
    }
}

// ---------------------------------------------------------------------------
// One-shot weight prep (merged): Wsd[256][256], wih[384][256], whh[384][128]
// ---------------------------------------------------------------------------
__global__ __launch_bounds__(256)
void prep_weights_kernel(const float* __restrict__ W_msg,
                         const float* __restrict__ w_ih,
                         const float* __restrict__ w_hh,
                         bf16* __restrict__ Wsd,
                         bf16* __restrict__ wih,
                         bf16* __restrict__ whh) {
    int gid = blockIdx.x * 256 + threadIdx.x;
    if (gid < 65536) {                 // Wsd: S rows then D rows
        int jj = gid >> 8, k = gid & 255;
        float v = (jj < 128) ? W_msg[jj * 512 + k]
                             : W_msg[(jj - 128) * 512 + 256 + k];
        Wsd[gid] = __float2bfloat16(v);
    } else if (gid < 65536 + 98304) {  // wih flat copy
        int i = gid - 65536;
        wih[i] = __float2bfloat16(w_ih[i]);
    } else if (gid < 65536 + 98304 + 49152) {
        int i = gid - 65536 - 98304;
        whh[i] = __float2bfloat16(w_hh[i]);
    }
}

// x -> XH[:, :128] and XC[:, :128]; h0 -> XH[:, 128:]
__global__ __launch_bounds__(256)
void conv_xh_kernel(const float* __restrict__ x, const float* __restrict__ h0,
                    bf16* __restrict__ XH, bf16* __restrict__ XC, int N) {
    int gid = blockIdx.x * 256 + threadIdx.x;
    int v = gid >> 7, j = gid & 127;
    if (v >= N) return;
    bf16 bx = __float2bfloat16(x[gid]);
    XH[(size_t)v * 256 + j] = bx;
    XC[(size_t)v * 256 + j] = bx;
    XH[(size_t)v * 256 + 128 + j] = __float2bfloat16(h0[gid]);
}

// ---------------------------------------------------------------------------
// CSR build (graph fixed across rounds)
// ---------------------------------------------------------------------------
__global__ __launch_bounds__(256)
void deg_kernel(const int* __restrict__ dst, int* __restrict__ cnt, int E) {
    int e = blockIdx.x * 256 + threadIdx.x;
    if (e < E) atomicAdd(&cnt[dst[e]], 1);
}

__global__ __launch_bounds__(256)
void csr_alloc_kernel(const int* __restrict__ cnt, int* __restrict__ off,
                      int* __restrict__ total, int N) {
    int v = blockIdx.x * 256 + threadIdx.x;
    int lane = threadIdx.x & 63;
    int c = (v < N) ? cnt[v] : 0;
    int s = c;
    #pragma unroll
    for (int d = 1; d < 64; d <<= 1) {
        int t = __shfl_up(s, d, 64);
        if (lane >= d) s += t;
    }
    int wave_total = __shfl(s, 63, 64);
    int base = 0;
    if (lane == 63) base = atomicAdd(total, wave_total);
    base = __shfl(base, 63, 64);
    if (v < N) off[v] = base + s - c;
}

__global__ __launch_bounds__(256)
void fill_csr_kernel(const int* __restrict__ src, const int* __restrict__ dst,
                     const int* __restrict__ off, int* __restrict__ cursor,
                     int* __restrict__ csr, int E) {
    int e = blockIdx.x * 256 + threadIdx.x;
    if (e >= E) return;
    int d = dst[e];
    int pos = atomicAdd(&cursor[d], 1);
    csr[off[d] + pos] = src[e];
}

// ---------------------------------------------------------------------------
// Gather-aggregate + fused mean/D/bias epilogue -> XC[:, 128:] (bf16)
// ---------------------------------------------------------------------------
__global__ __launch_bounds__(256)
void agg_kernel(const bf16* __restrict__ SD, const int* __restrict__ csr,
                const int* __restrict__ off, const int* __restrict__ cnt,
                const float* __restrict__ b_msg, bf16* __restrict__ XC, int N) {
    const int v    = (blockIdx.x * 256 + threadIdx.x) >> 6;
    const int lane = threadIdx.x & 63;
    if (v >= N) return;
    const int deg  = cnt[v];
    const int base = off[v];

    float ax[4] = {0.f, 0.f, 0.f, 0.f};
    float ay[4] = {0.f, 0.f, 0.f, 0.f};
    int k = 0;
    for (; k + 3 < deg; k += 4) {
        #pragma unroll
        for (int u = 0; u < 4; ++u) {
            int s0 = csr[base + k + u];
            unsigned q = *reinterpret_cast<const unsigned*>(
                SD + (size_t)s0 * 256 + lane * 2);
            ax[u] += __uint_as_float(q << 16);
            ay[u] += __uint_as_float(q & 0xffff0000u);
        }
    }
    for (; k < deg; ++k) {
        int s0 = csr[base + k];
        unsigned q = *reinterpret_cast<const unsigned*>(
            SD + (size_t)s0 * 256 + lane * 2);
        ax[0] += __uint_as_float(q << 16);
        ay[0] += __uint_as_float(q & 0xffff0000u);
    }

    float ox = 0.f, oy = 0.f;
    if (deg > 0) {
        unsigned ud = *reinterpret_cast<const unsigned*>(SD + (size_t)v * 256 + 128 + lane * 2);
        float inv = 1.0f / (float)deg;
        const float2 bm = *reinterpret_cast<const float2*>(b_msg + lane * 2);
        ox = ((ax[0] + ax[1]) + (ax[2] + ax[3])) * inv + __uint_as_float(ud << 16)         + bm.x;
        oy = ((ay[0] + ay[1]) + (ay[2] + ay[3])) * inv + __uint_as_float(ud & 0xffff0000u) + bm.y;
    }
    __hip_bfloat162 o2;
    o2.x = __float2bfloat16(ox);
    o2.y = __float2bfloat16(oy);
    *reinterpret_cast<__hip_bfloat162*>(XC + (size_t)v * 256 + 128 + lane * 2) = o2;
}

// ---------------------------------------------------------------------------
extern "C" void kernel_launch(void* const* d_in, const int* in_sizes, int n_in,
                              void* d_out, int out_size, void* d_ws, size_t ws_size,
                              hipStream_t stream) {
    const float* x     = (const float*)d_in[0];
    const float* h0    = (const float*)d_in[1];
    const float* W_msg = (const float*)d_in[2];
    const float* b_msg = (const float*)d_in[3];
    const float* w_ih  = (const float*)d_in[4];
    const float* w_hh  = (const float*)d_in[5];
    const float* b_ih  = (const float*)d_in[6];
    const float* b_hh  = (const float*)d_in[7];
    const int*   src   = (const int*)d_in[8];
    const int*   dst   = (const int*)d_in[9];
    float* h = (float*)d_out;

    char* ws = (char*)d_ws;
    size_t off_b = 0;
    auto alloc = [&](size_t bytes) -> void* {
        void* p = ws + off_b;
        off_b = (off_b + bytes + 255) & ~(size_t)255;
        return p;
    };
    int*  meta   = (int*) alloc(((size_t)2 * N_NODES + 64) * 4);
    int*  cnt    = meta;
    int*  cursor = meta + N_NODES;
    int*  total  = meta + 2 * N_NODES;
    int*  off    = (int*) alloc((size_t)N_NODES * 4);
    int*  csr    = (int*) alloc((size_t)N_EDGES * 4);
    bf16* Wsd_b  = (bf16*)alloc(256 * 256 * 2);
    bf16* wih_b  = (bf16*)alloc(384 * 256 * 2);
    bf16* whh_b  = (bf16*)alloc(384 * 128 * 2);
    bf16* XH     = (bf16*)alloc((size_t)N_NODES * 256 * 2);
    bf16* XC     = (bf16*)alloc((size_t)N_NODES * 256 * 2);
    bf16* SD     = (bf16*)alloc((size_t)N_NODES * 256 * 2);
    bf16* GI     = (bf16*)alloc((size_t)N_NODES * 384 * 2);

    // --- one-time: CSR + conversions ---
    hipMemsetAsync(meta, 0, ((size_t)2 * N_NODES + 64) * 4, stream);
    deg_kernel<<<(N_EDGES + 255) / 256, 256, 0, stream>>>(dst, cnt, N_EDGES);
    csr_alloc_kernel<<<(N_NODES + 255) / 256, 256, 0, stream>>>(cnt, off, total, N_NODES);
    fill_csr_kernel<<<(N_EDGES + 255) / 256, 256, 0, stream>>>(src, dst, off, cursor,
                                                               csr, N_EDGES);
    prep_weights_kernel<<<(65536 + 98304 + 49152 + 255) / 256, 256, 0, stream>>>(
        W_msg, w_ih, w_hh, Wsd_b, wih_b, whh_b);
    conv_xh_kernel<<<(N_NODES * 128 + 255) / 256, 256, 0, stream>>>(x, h0, XH, XC, N_NODES);

    const int MB  = (N_NODES + 255) / 256;   // 196 (BM=256 gemms)
    const int MB2 = (N_NODES + 63) / 64;     // 782 (fused ghgru)
    dim3 blk(256);

    for (int r = 0; r < 2; ++r) {
        // SD = XH @ Wsd^T
        gemm_mfma_kernel<256><<<dim3(MB, 4), blk, 0, stream>>>(
            XH, Wsd_b, nullptr, SD, N_NODES, 256);
        // c -> XC[:,128:]
        agg_kernel<<<(N_NODES * 64 + 255) / 256, blk, 0, stream>>>(
            SD, csr, off, cnt, b_msg, XC, N_NODES);
        // GI = XC @ w_ih^T + b_ih
        gemm_mfma_kernel<256><<<dim3(MB, 6), blk, 0, stream>>>(
            XC, wih_b, b_ih, GI, N_NODES, 384);
        // GH + GRU fused: h_new = gru(GI, h @ w_hh^T + b_hh, h_in)
        if (r == 0) {
            ghgru_kernel<0><<<MB2, blk, 0, stream>>>(
                XH, whh_b, b_hh, GI, h0, nullptr, XH, N_NODES);
        } else {
            ghgru_kernel<1><<<MB2, blk, 0, stream>>>(
                XH, whh_b, b_hh, GI, nullptr, h, nullptr, N_NODES);
        }
    }
}

// Round 8
// 301.396 us; speedup vs baseline: 13.2693x; 1.1153x over previous
//
#include <hip/hip_runtime.h>
#include <hip/hip_bf16.h>

typedef __hip_bfloat16 bf16;
typedef __bf16 bf16x8 __attribute__((ext_vector_type(8)));
typedef float  f32x4  __attribute__((ext_vector_type(4)));

#define N_NODES 50000
#define N_EDGES 400000
#define HID 128
#define MSG 128
#define LDXA 256   // XA row stride: [x(128) | c(128)] ; h lives in Hb0/Hb1

// ---------------------------------------------------------------------------
// SD GEMM: SD[M,256] = [x|h] @ Wsd^T.  x from XA cols 0..127, h from Hb.
// BM=256, BN=64, 4 waves. Ws XOR-swizzled; epilogue via LDS. (R5-proven)
// ---------------------------------------------------------------------------
__global__ __launch_bounds__(256)
void gemm_sd_kernel(const bf16* __restrict__ XA,
                    const bf16* __restrict__ Hb,     // [N,128] bf16 h
                    const bf16* __restrict__ W,      // [256,256]
                    bf16* __restrict__ O, int M) {
    constexpr int K = 256, J = 256, KC = K >> 3;
    __shared__ bf16 Ws[64 * K];                      // 32KB; reused for C tile

    const int tid = threadIdx.x;
    const int bm = blockIdx.x * 256;
    const int bn = blockIdx.y * 64;

    for (int c = tid; c < 64 * KC; c += 256) {
        int j  = c / KC;
        int kc = c % KC;
        const float4 v = *reinterpret_cast<const float4*>(
            W + (size_t)(bn + j) * K + kc * 8);
        *reinterpret_cast<float4*>(&Ws[(kc * 64 + (j ^ (kc & 7))) * 8]) = v;
    }
    __syncthreads();

    const int w    = tid >> 6;
    const int lane = tid & 63;
    const int lr   = lane & 15;
    const int kg   = lane >> 4;
    const int mbase = bm + w * 64;

    const bf16* Ax[4];
    const bf16* Ah[4];
    #pragma unroll
    for (int fm = 0; fm < 4; ++fm) {
        int m = mbase + fm * 16 + lr;
        if (m >= M) m = M - 1;
        Ax[fm] = XA + (size_t)m * LDXA + kg * 8;
        Ah[fm] = Hb + (size_t)m * 128 + kg * 8;
    }

    f32x4 acc[4][4] = {};

    #pragma unroll
    for (int k0 = 0; k0 < K; k0 += 32) {
        bf16x8 a[4];
        #pragma unroll
        for (int fm = 0; fm < 4; ++fm)
            a[fm] = (k0 < 128)
                ? *reinterpret_cast<const bf16x8*>(Ax[fm] + k0)
                : *reinterpret_cast<const bf16x8*>(Ah[fm] + (k0 - 128));
        const int kcb = (k0 >> 3) + kg;
        #pragma unroll
        for (int fn = 0; fn < 4; ++fn) {
            bf16x8 b = *reinterpret_cast<const bf16x8*>(
                &Ws[(kcb * 64 + ((fn * 16 + lr) ^ (kcb & 7))) * 8]);
            #pragma unroll
            for (int fm = 0; fm < 4; ++fm)
                acc[fm][fn] = __builtin_amdgcn_mfma_f32_16x16x32_bf16(
                    a[fm], b, acc[fm][fn], 0, 0, 0);
        }
    }

    __syncthreads();
    #pragma unroll
    for (int fn = 0; fn < 4; ++fn) {
        int col = fn * 16 + lr;
        #pragma unroll
        for (int fm = 0; fm < 4; ++fm) {
            int rbase = w * 64 + fm * 16 + kg * 4;
            #pragma unroll
            for (int r = 0; r < 4; ++r) {
                int row = rbase + r;
                int cs = ((((col >> 3) ^ ((row >> 2) & 7))) << 3) | (col & 7);
                Ws[row * 64 + cs] = __float2bfloat16(acc[fm][fn][r]);
            }
        }
    }
    __syncthreads();
    const int colblk = tid & 7;
    const int rbase_o = tid >> 3;
    #pragma unroll
    for (int it = 0; it < 8; ++it) {
        int row = it * 32 + rbase_o;
        int grow = bm + row;
        if (grow < M) {
            int g = (row >> 2) & 7;
            const float4 v = *reinterpret_cast<const float4*>(
                &Ws[row * 64 + ((colblk ^ g) << 3)]);
            *reinterpret_cast<float4*>(O + (size_t)grow * J + bn + colblk * 8) = v;
        }
    }
}

// ---------------------------------------------------------------------------
// Fused gates GEMM + GRU.  G[M,512] = [x|c|h] @ Wg^T, Wg quad-interleaved:
// row j' = jhalf*256 + q*64 + g*16 + lr  ->  gate g of hid col c=jhalf*64+q*16+lr
//   g=0 (r): [w_ih_r | w_hh_r]   g=1 (z): [w_ih_z | w_hh_z]
//   g=2 (i_n): [w_ih_n | 0]      g=3 (h_n): [0 | w_hh_n]
// A chunks: ck=0 -> XA x, ck=1 -> XA c, ck=2 -> Hb h (ping-pong: reads Hin,
// writes Hout -- NO aliasing, fixes the R7 cross-block race).
// Block: 512 thr = 8 waves, BM=128 (16 rows/wave), 16 n-frags (J-half 256).
// Epilogue: quad = 4 consecutive acc frags, GRU fully in-register.
// ---------------------------------------------------------------------------
__device__ __forceinline__ float fast_sigmoid(float x) {
    return 1.0f / (1.0f + __expf(-x));
}
__device__ __forceinline__ float fast_tanh(float x) {
    float e = __expf(-2.0f * fabsf(x));
    float t = (1.0f - e) / (1.0f + e);
    return copysignf(t, x);
}

template <int FINAL>
__global__ __launch_bounds__(512)
void gates_kernel(const bf16* __restrict__ XA,
                  const bf16* __restrict__ Hin,    // [N,128] bf16 h (read)
                  const bf16* __restrict__ Wg,     // [512,384] interleaved
                  const float* __restrict__ bg,    // [512] fused bias
                  const float* __restrict__ h0,    // f32 h_in (round 0)
                  float* __restrict__ h_out,       // f32 out (FINAL)
                  bf16* __restrict__ Hout,         // bf16 h out (non-final)
                  int M) {
    __shared__ bf16 Ws[16 * 256 * 8];              // 64KB: [kc][j 0..255][8]

    const int tid   = threadIdx.x;
    const int w     = tid >> 6;
    const int lane  = tid & 63;
    const int lr    = lane & 15;
    const int kg    = lane >> 4;
    const int jhalf = blockIdx.y;
    const int mbase = blockIdx.x * 128 + w * 16;

    int arow = mbase + lr;
    if (arow >= M) arow = M - 1;
    const bf16* Abase[3] = {
        XA + (size_t)arow * LDXA + kg * 8,          // x
        XA + (size_t)arow * LDXA + 128 + kg * 8,    // c
        Hin + (size_t)arow * 128 + kg * 8           // h
    };
    const bf16* Wbase = Wg + (size_t)jhalf * 256 * 384;

    f32x4 acc[16];
    #pragma unroll
    for (int i = 0; i < 16; ++i) acc[i] = f32x4{0.f, 0.f, 0.f, 0.f};

    #pragma unroll
    for (int ck = 0; ck < 3; ++ck) {               // K chunks of 128
        if (ck) __syncthreads();
        for (int c = tid; c < 256 * 16; c += 512) {
            int j  = c >> 4;
            int kc = c & 15;
            const float4 v = *reinterpret_cast<const float4*>(
                Wbase + (size_t)j * 384 + ck * 128 + kc * 8);
            *reinterpret_cast<float4*>(&Ws[(kc * 256 + (j ^ (kc & 7))) * 8]) = v;
        }
        __syncthreads();
        bf16x8 a[4];
        #pragma unroll
        for (int k0 = 0; k0 < 4; ++k0)
            a[k0] = *reinterpret_cast<const bf16x8*>(Abase[ck] + k0 * 32);
        #pragma unroll
        for (int fn = 0; fn < 16; ++fn) {
            #pragma unroll
            for (int k0 = 0; k0 < 4; ++k0) {
                const int kcb = k0 * 4 + kg;
                bf16x8 b = *reinterpret_cast<const bf16x8*>(
                    &Ws[(kcb * 256 + ((fn * 16 + lr) ^ (kcb & 7))) * 8]);
                acc[fn] = __builtin_amdgcn_mfma_f32_16x16x32_bf16(
                    a[k0], b, acc[fn], 0, 0, 0);
            }
        }
    }

    // ---- fused GRU epilogue (quad = frags 4q..4q+3, lane-local) ----
    #pragma unroll
    for (int q = 0; q < 4; ++q) {
        const int jq = jhalf * 256 + q * 64;
        const float br  = bg[jq + lr];
        const float bz  = bg[jq + 16 + lr];
        const float bin = bg[jq + 32 + lr];
        const float bhn = bg[jq + 48 + lr];
        const int c = jhalf * 64 + q * 16 + lr;    // hid col
        #pragma unroll
        for (int r = 0; r < 4; ++r) {
            const int row = mbase + kg * 4 + r;
            if (row >= M) continue;
            float rr = fast_sigmoid(acc[4 * q + 0][r] + br);
            float zz = fast_sigmoid(acc[4 * q + 1][r] + bz);
            float nn = fast_tanh(acc[4 * q + 2][r] + bin +
                                 rr * (acc[4 * q + 3][r] + bhn));
            float hin;
            if (FINAL) {
                hin = __bfloat162float(Hin[(size_t)row * 128 + c]);
            } else {
                hin = h0[(size_t)row * 128 + c];
            }
            float hv = (1.0f - zz) * nn + zz * hin;
            if (FINAL) {
                h_out[(size_t)row * 128 + c] = hv;
            } else {
                Hout[(size_t)row * 128 + c] = __float2bfloat16(hv);
            }
        }
    }
}

// ---------------------------------------------------------------------------
// One-shot weight prep: Wsd[256][256], Wg[512][384] (quad-interleaved), bg[512]
// ---------------------------------------------------------------------------
#define WSD_N  65536
#define WG_N   196608
__global__ __launch_bounds__(256)
void prep_weights_kernel(const float* __restrict__ W_msg,
                         const float* __restrict__ w_ih,
                         const float* __restrict__ w_hh,
                         const float* __restrict__ b_ih,
                         const float* __restrict__ b_hh,
                         bf16* __restrict__ Wsd,
                         bf16* __restrict__ Wg,
                         float* __restrict__ bg) {
    int gid = blockIdx.x * 256 + threadIdx.x;
    if (gid < WSD_N) {                 // Wsd: S rows then D rows
        int jj = gid >> 8, k = gid & 255;
        float v = (jj < 128) ? W_msg[jj * 512 + k]
                             : W_msg[(jj - 128) * 512 + 256 + k];
        Wsd[gid] = __float2bfloat16(v);
    } else if (gid < WSD_N + WG_N) {
        int i = gid - WSD_N;
        int jp = i / 384, k = i % 384;
        int jhalf = jp >> 8, rest = jp & 255;
        int q = rest >> 6, g = (rest >> 4) & 3, lr = rest & 15;
        int c = jhalf * 64 + q * 16 + lr;
        float v;
        if (k < 256) v = (g < 3) ? w_ih[(size_t)(g * 128 + c) * 256 + k] : 0.0f;
        else         v = (g == 2) ? 0.0f
                       : w_hh[(size_t)(((g == 3) ? 2 : g) * 128 + c) * 128 + (k - 256)];
        Wg[i] = __float2bfloat16(v);
    } else if (gid < WSD_N + WG_N + 512) {
        int jp = gid - WSD_N - WG_N;
        int jhalf = jp >> 8, rest = jp & 255;
        int q = rest >> 6, g = (rest >> 4) & 3, lr = rest & 15;
        int c = jhalf * 64 + q * 16 + lr;
        float v;
        if (g == 0)      v = b_ih[c] + b_hh[c];
        else if (g == 1) v = b_ih[128 + c] + b_hh[128 + c];
        else if (g == 2) v = b_ih[256 + c];
        else             v = b_hh[256 + c];
        bg[jp] = v;
    }
}

// x -> XA[:, :128]; h0 -> Hb0 (bf16)
__global__ __launch_bounds__(256)
void conv_xa_kernel(const float* __restrict__ x, const float* __restrict__ h0,
                    bf16* __restrict__ XA, bf16* __restrict__ Hb0, int N) {
    int gid = blockIdx.x * 256 + threadIdx.x;
    int v = gid >> 7, j = gid & 127;
    if (v >= N) return;
    XA[(size_t)v * LDXA + j] = __float2bfloat16(x[gid]);
    Hb0[gid]                 = __float2bfloat16(h0[gid]);
}

// ---------------------------------------------------------------------------
// CSR build (graph fixed across rounds)
// ---------------------------------------------------------------------------
__global__ __launch_bounds__(256)
void deg_kernel(const int* __restrict__ dst, int* __restrict__ cnt, int E) {
    int e = blockIdx.x * 256 + threadIdx.x;
    if (e < E) atomicAdd(&cnt[dst[e]], 1);
}

__global__ __launch_bounds__(256)
void csr_alloc_kernel(const int* __restrict__ cnt, int* __restrict__ off,
                      int* __restrict__ total, int N) {
    int v = blockIdx.x * 256 + threadIdx.x;
    int lane = threadIdx.x & 63;
    int c = (v < N) ? cnt[v] : 0;
    int s = c;
    #pragma unroll
    for (int d = 1; d < 64; d <<= 1) {
        int t = __shfl_up(s, d, 64);
        if (lane >= d) s += t;
    }
    int wave_total = __shfl(s, 63, 64);
    int base = 0;
    if (lane == 63) base = atomicAdd(total, wave_total);
    base = __shfl(base, 63, 64);
    if (v < N) off[v] = base + s - c;
}

__global__ __launch_bounds__(256)
void fill_csr_kernel(const int* __restrict__ src, const int* __restrict__ dst,
                     const int* __restrict__ off, int* __restrict__ cursor,
                     int* __restrict__ csr, int E) {
    int e = blockIdx.x * 256 + threadIdx.x;
    if (e >= E) return;
    int d = dst[e];
    int pos = atomicAdd(&cursor[d], 1);
    csr[off[d] + pos] = src[e];
}

// ---------------------------------------------------------------------------
// Gather-aggregate + fused mean/D/bias epilogue -> XA[:, 128:256] (bf16)
// ---------------------------------------------------------------------------
__global__ __launch_bounds__(256)
void agg_kernel(const bf16* __restrict__ SD, const int* __restrict__ csr,
                const int* __restrict__ off, const int* __restrict__ cnt,
                const float* __restrict__ b_msg, bf16* __restrict__ XA, int N) {
    const int v    = (blockIdx.x * 256 + threadIdx.x) >> 6;
    const int lane = threadIdx.x & 63;
    if (v >= N) return;
    const int deg  = cnt[v];
    const int base = off[v];

    float ax[4] = {0.f, 0.f, 0.f, 0.f};
    float ay[4] = {0.f, 0.f, 0.f, 0.f};
    int k = 0;
    for (; k + 3 < deg; k += 4) {
        #pragma unroll
        for (int u = 0; u < 4; ++u) {
            int s0 = csr[base + k + u];
            unsigned q = *reinterpret_cast<const unsigned*>(
                SD + (size_t)s0 * 256 + lane * 2);
            ax[u] += __uint_as_float(q << 16);
            ay[u] += __uint_as_float(q & 0xffff0000u);
        }
    }
    for (; k < deg; ++k) {
        int s0 = csr[base + k];
        unsigned q = *reinterpret_cast<const unsigned*>(
            SD + (size_t)s0 * 256 + lane * 2);
        ax[0] += __uint_as_float(q << 16);
        ay[0] += __uint_as_float(q & 0xffff0000u);
    }

    float ox = 0.f, oy = 0.f;
    if (deg > 0) {
        unsigned ud = *reinterpret_cast<const unsigned*>(
            SD + (size_t)v * 256 + 128 + lane * 2);
        float inv = 1.0f / (float)deg;
        const float2 bm = *reinterpret_cast<const float2*>(b_msg + lane * 2);
        ox = ((ax[0] + ax[1]) + (ax[2] + ax[3])) * inv + __uint_as_float(ud << 16)         + bm.x;
        oy = ((ay[0] + ay[1]) + (ay[2] + ay[3])) * inv + __uint_as_float(ud & 0xffff0000u) + bm.y;
    }
    __hip_bfloat162 o2;
    o2.x = __float2bfloat16(ox);
    o2.y = __float2bfloat16(oy);
    *reinterpret_cast<__hip_bfloat162*>(XA + (size_t)v * LDXA + 128 + lane * 2) = o2;
}

// ---------------------------------------------------------------------------
extern "C" void kernel_launch(void* const* d_in, const int* in_sizes, int n_in,
                              void* d_out, int out_size, void* d_ws, size_t ws_size,
                              hipStream_t stream) {
    const float* x     = (const float*)d_in[0];
    const float* h0    = (const float*)d_in[1];
    const float* W_msg = (const float*)d_in[2];
    const float* b_msg = (const float*)d_in[3];
    const float* w_ih  = (const float*)d_in[4];
    const float* w_hh  = (const float*)d_in[5];
    const float* b_ih  = (const float*)d_in[6];
    const float* b_hh  = (const float*)d_in[7];
    const int*   src   = (const int*)d_in[8];
    const int*   dst   = (const int*)d_in[9];
    float* h = (float*)d_out;

    char* ws = (char*)d_ws;
    size_t off_b = 0;
    auto alloc = [&](size_t bytes) -> void* {
        void* p = ws + off_b;
        off_b = (off_b + bytes + 255) & ~(size_t)255;
        return p;
    };
    int*   meta   = (int*)  alloc(((size_t)2 * N_NODES + 64) * 4);
    int*   cnt    = meta;
    int*   cursor = meta + N_NODES;
    int*   total  = meta + 2 * N_NODES;
    int*   off    = (int*)  alloc((size_t)N_NODES * 4);
    int*   csr    = (int*)  alloc((size_t)N_EDGES * 4);
    bf16*  Wsd_b  = (bf16*) alloc((size_t)WSD_N * 2);
    bf16*  Wg_b   = (bf16*) alloc((size_t)WG_N * 2);
    float* bg     = (float*)alloc(512 * 4);
    bf16*  XA     = (bf16*) alloc((size_t)N_NODES * LDXA * 2);
    bf16*  Hb0    = (bf16*) alloc((size_t)N_NODES * 128 * 2);
    bf16*  Hb1    = (bf16*) alloc((size_t)N_NODES * 128 * 2);
    bf16*  SD     = (bf16*) alloc((size_t)N_NODES * 256 * 2);

    // --- one-time: CSR + conversions + weight prep ---
    hipMemsetAsync(meta, 0, ((size_t)2 * N_NODES + 64) * 4, stream);
    deg_kernel<<<(N_EDGES + 255) / 256, 256, 0, stream>>>(dst, cnt, N_EDGES);
    csr_alloc_kernel<<<(N_NODES + 255) / 256, 256, 0, stream>>>(cnt, off, total, N_NODES);
    fill_csr_kernel<<<(N_EDGES + 255) / 256, 256, 0, stream>>>(src, dst, off, cursor,
                                                               csr, N_EDGES);
    prep_weights_kernel<<<(WSD_N + WG_N + 512 + 255) / 256, 256, 0, stream>>>(
        W_msg, w_ih, w_hh, b_ih, b_hh, Wsd_b, Wg_b, bg);
    conv_xa_kernel<<<(N_NODES * 128 + 255) / 256, 256, 0, stream>>>(x, h0, XA, Hb0, N_NODES);

    const int MB  = (N_NODES + 255) / 256;   // 196  (SD gemm)
    const int MBG = (N_NODES + 127) / 128;   // 391  (gates)

    // ---- round 0: h = Hb0 -> Hb1 ----
    gemm_sd_kernel<<<dim3(MB, 4), 256, 0, stream>>>(XA, Hb0, Wsd_b, SD, N_NODES);
    agg_kernel<<<(N_NODES * 64 + 255) / 256, 256, 0, stream>>>(
        SD, csr, off, cnt, b_msg, XA, N_NODES);
    gates_kernel<0><<<dim3(MBG, 2), 512, 0, stream>>>(
        XA, Hb0, Wg_b, bg, h0, nullptr, Hb1, N_NODES);

    // ---- round 1 (final): h = Hb1 -> d_out ----
    gemm_sd_kernel<<<dim3(MB, 4), 256, 0, stream>>>(XA, Hb1, Wsd_b, SD, N_NODES);
    agg_kernel<<<(N_NODES * 64 + 255) / 256, 256, 0, stream>>>(
        SD, csr, off, cnt, b_msg, XA, N_NODES);
    gates_kernel<1><<<dim3(MBG, 2), 512, 0, stream>>>(
        XA, Hb1, Wg_b, bg, nullptr, h, nullptr, N_NODES);
}